// Round 2
// baseline (1662.090 us; speedup 1.0000x reference)
//
#include <hip/hip_runtime.h>
#include <math.h>

#define NPIX 12544   // B*H*W = 4*56*56
#define CH   128
#define HEADS 4
#define HD   32
#define KS   7
#define HID  512
#define HH   56
#define WW   56

__device__ inline float gelu_f(float x) { return 0.5f * x * (1.0f + erff(x * 0.70710678118654752f)); }

// ---------------- copy f32 (duplicated into two state buffers) ----------------
__global__ __launch_bounds__(256) void dup_kernel(const float* __restrict__ in,
    float* __restrict__ o1, float* __restrict__ o2, int n4)
{
    int i = blockIdx.x * 256 + threadIdx.x;
    if (i < n4) {
        float4 v = reinterpret_cast<const float4*>(in)[i];
        reinterpret_cast<float4*>(o1)[i] = v;
        if (o2) reinterpret_cast<float4*>(o2)[i] = v;
    }
}

// ---------------- LayerNorm over C=128, one wave per row ----------------
__global__ __launch_bounds__(64) void ln128_kernel(const float* __restrict__ in,
    const float* __restrict__ g, const float* __restrict__ b, float* __restrict__ out)
{
    int p = blockIdx.x, lane = threadIdx.x;
    float2 v = reinterpret_cast<const float2*>(in + (size_t)p * CH)[lane];
    float s = v.x + v.y, sq = v.x * v.x + v.y * v.y;
#pragma unroll
    for (int o = 32; o > 0; o >>= 1) { s += __shfl_xor(s, o); sq += __shfl_xor(sq, o); }
    float mean = s * (1.0f / CH);
    float inv = rsqrtf(sq * (1.0f / CH) - mean * mean + 1e-5f);
    float2 gg = reinterpret_cast<const float2*>(g)[lane];
    float2 bb = reinterpret_cast<const float2*>(b)[lane];
    float2 o;
    o.x = (v.x - mean) * inv * gg.x + bb.x;
    o.y = (v.y - mean) * inv * gg.y + bb.y;
    reinterpret_cast<float2*>(out + (size_t)p * CH)[lane] = o;
}

// ---------------- Tiled GEMM: A[M,K] f32 x B[K,N] f32 -> C[M,N] f32 ----------------
// mode 0: +bias ; mode 1: gelu(+bias) ; mode 2: +bias + res
__global__ __launch_bounds__(256) void gemm_kernel(
    const float* __restrict__ A, const float* __restrict__ Bw,
    const float* __restrict__ bias, const float* __restrict__ res,
    float* __restrict__ C, int M, int N, int K, int mode)
{
    __shared__ float As[64][17];
    __shared__ float Bs[16][68];
    int t = threadIdx.x;
    int m0 = blockIdx.x * 64, n0 = blockIdx.y * 64;
    int tx = t & 15, ty = t >> 4;
    int ar = t >> 2, ac = (t & 3) * 4;
    int br = t >> 4, bc = (t & 15) * 4;
    float acc[4][4] = {};
    for (int k0 = 0; k0 < K; k0 += 16) {
        float4 av = *reinterpret_cast<const float4*>(A + (size_t)(m0 + ar) * K + k0 + ac);
        As[ar][ac + 0] = av.x; As[ar][ac + 1] = av.y; As[ar][ac + 2] = av.z; As[ar][ac + 3] = av.w;
        float4 bv = *reinterpret_cast<const float4*>(Bw + (size_t)(k0 + br) * N + n0 + bc);
        Bs[br][bc + 0] = bv.x; Bs[br][bc + 1] = bv.y;
        Bs[br][bc + 2] = bv.z; Bs[br][bc + 3] = bv.w;
        __syncthreads();
#pragma unroll
        for (int kk = 0; kk < 16; ++kk) {
            float a[4], bb[4];
#pragma unroll
            for (int i2 = 0; i2 < 4; ++i2) a[i2] = As[ty * 4 + i2][kk];
#pragma unroll
            for (int j2 = 0; j2 < 4; ++j2) bb[j2] = Bs[kk][tx * 4 + j2];
#pragma unroll
            for (int i2 = 0; i2 < 4; ++i2)
#pragma unroll
                for (int j2 = 0; j2 < 4; ++j2) acc[i2][j2] += a[i2] * bb[j2];
        }
        __syncthreads();
    }
#pragma unroll
    for (int i2 = 0; i2 < 4; ++i2) {
        int row = m0 + ty * 4 + i2;
#pragma unroll
        for (int j2 = 0; j2 < 4; ++j2) {
            int col = n0 + tx * 4 + j2;
            float v = acc[i2][j2] + bias[col];
            if (mode == 1) v = gelu_f(v);
            else if (mode == 2) v += res[(size_t)row * N + col];
            C[(size_t)row * N + col] = v;
        }
    }
}

// ---------------- Neighborhood attention: 1 block/pixel, 1 wave/head ----------------
__global__ __launch_bounds__(256) void na_kernel(
    const float* __restrict__ Q, int qld,
    const float* __restrict__ Kx, const float* __restrict__ Vx, int kvld,
    const float* __restrict__ rpb, float* __restrict__ Out)
{
    __shared__ float qs[HEADS][HD];
    __shared__ float as_[HEADS][64];
    __shared__ int pns[HEADS][49];
    int p = blockIdx.x;
    int bidx = p / (HH * WW); int rem = p % (HH * WW);
    int i = rem / WW, j = rem % WW;
    int h = threadIdx.x >> 6, lane = threadIdx.x & 63;

    if (lane < HD) qs[h][lane] = Q[(size_t)p * qld + h * HD + lane];
    int si = min(max(i - 3, 0), HH - KS), sj = min(max(j - 3, 0), WW - KS);
    int pn = 0, ri = 0, rj = 0;
    if (lane < 49) {
        int ai = lane / 7, aj = lane - ai * 7;
        int ni = si + ai, nj = sj + aj;
        pn = (bidx * HH + ni) * WW + nj;
        pns[h][lane] = pn;
        ri = ni - i + 6; rj = nj - j + 6;
    }
    __syncthreads();
    float s = -1e30f;
    if (lane < 49) {
        const float* kp = Kx + (size_t)pn * kvld + h * HD;
        float dot = 0.f;
#pragma unroll
        for (int d = 0; d < HD; ++d) dot += qs[h][d] * kp[d];
        s = dot * 0.17677669529663687f + rpb[h * 169 + ri * 13 + rj];
    }
    float m = s;
#pragma unroll
    for (int o = 32; o > 0; o >>= 1) m = fmaxf(m, __shfl_xor(m, o));
    float e = (lane < 49) ? expf(s - m) : 0.f;
    float sum = e;
#pragma unroll
    for (int o = 32; o > 0; o >>= 1) sum += __shfl_xor(sum, o);
    as_[h][lane] = e / sum;
    __syncthreads();
    if (lane < HD) {
        float o = 0.f;
        for (int mm = 0; mm < 49; ++mm)
            o += as_[h][mm] * Vx[(size_t)pns[h][mm] * kvld + h * HD + lane];
        Out[(size_t)p * CH + h * HD + lane] = o;
    }
}

// ---------------- 3x3 stride-2 conv, 256 in (concat of two 128 bufs) -> 512 out ----------------
__global__ __launch_bounds__(256) void conv_kernel(
    const float* __restrict__ X1, const float* __restrict__ X2,
    const float* __restrict__ Wt, float* __restrict__ Out)
{
    __shared__ float patch[2304];
    int p = blockIdx.x;                       // 0..3135  (b,oi,oj)
    int bidx = p / 784; int rem = p % 784; int oi = rem / 28, oj = rem % 28;
    int t = threadIdx.x;
    for (int e = t; e < 2304; e += 256) {
        int ky = e / 768; int r2 = e - ky * 768; int kx = r2 >> 8; int ch = r2 & 255;
        int ii = oi * 2 - 1 + ky, jj = oj * 2 - 1 + kx;
        float v = 0.f;
        if ((unsigned)ii < 56u && (unsigned)jj < 56u) {
            size_t pix = ((size_t)((bidx * 56 + ii) * 56 + jj)) * 128;
            v = (ch < 128) ? X1[pix + ch] : X2[pix + ch - 128];
        }
        patch[e] = v;
    }
    __syncthreads();
    float a0 = 0.f, a1 = 0.f;
#pragma unroll 4
    for (int e = 0; e < 2304; ++e) {
        float pv = patch[e];
        float2 w = *reinterpret_cast<const float2*>(Wt + (size_t)e * 512 + 2 * t);
        a0 += pv * w.x;
        a1 += pv * w.y;
    }
    Out[(size_t)p * 512 + 2 * t] = a0;
    Out[(size_t)p * 512 + 2 * t + 1] = a1;
}

// ---------------- final LayerNorm over 512, write f32 ----------------
__global__ __launch_bounds__(64) void ln512_out_kernel(const float* __restrict__ in,
    const float* __restrict__ g, const float* __restrict__ b, float* __restrict__ out)
{
    int p = blockIdx.x, lane = threadIdx.x;
    const float4* ip = reinterpret_cast<const float4*>(in + (size_t)p * 512);
    float4 v0 = ip[lane * 2], v1 = ip[lane * 2 + 1];
    float vals[8] = { v0.x, v0.y, v0.z, v0.w, v1.x, v1.y, v1.z, v1.w };
    float s = 0.f, sq = 0.f;
#pragma unroll
    for (int q = 0; q < 8; ++q) { s += vals[q]; sq += vals[q] * vals[q]; }
#pragma unroll
    for (int o = 32; o > 0; o >>= 1) { s += __shfl_xor(s, o); sq += __shfl_xor(sq, o); }
    float mean = s * (1.0f / 512.0f);
    float inv = rsqrtf(sq * (1.0f / 512.0f) - mean * mean + 1e-5f);
#pragma unroll
    for (int q = 0; q < 8; ++q) {
        int c = lane * 8 + q;
        out[(size_t)p * 512 + c] = (vals[q] - mean) * inv * g[c] + b[c];
    }
}

extern "C" void kernel_launch(void* const* d_in, const int* in_sizes, int n_in,
                              void* d_out, int out_size, void* d_ws, size_t ws_size,
                              hipStream_t stream)
{
    const float* X      = (const float*)d_in[0];
    const float* XM     = (const float*)d_in[1];
    const float* sa_n1g = (const float*)d_in[2];
    const float* sa_n1b = (const float*)d_in[3];
    const float* sa_qkvw= (const float*)d_in[4];
    const float* sa_qkvb= (const float*)d_in[5];
    const float* sa_rpb = (const float*)d_in[6];
    const float* sa_pw  = (const float*)d_in[7];
    const float* sa_pb  = (const float*)d_in[8];
    const float* sa_n2g = (const float*)d_in[9];
    const float* sa_n2b = (const float*)d_in[10];
    const float* sa_f1w = (const float*)d_in[11];
    const float* sa_f1b = (const float*)d_in[12];
    const float* sa_f2w = (const float*)d_in[13];
    const float* sa_f2b = (const float*)d_in[14];
    const float* cr_n1g = (const float*)d_in[15];
    const float* cr_n1b = (const float*)d_in[16];
    const float* cr_qw  = (const float*)d_in[17];
    const float* cr_qb  = (const float*)d_in[18];
    const float* cr_kvw = (const float*)d_in[19];
    const float* cr_kvb = (const float*)d_in[20];
    const float* cr_rpb = (const float*)d_in[21];
    const float* cr_pw  = (const float*)d_in[22];
    const float* cr_pb  = (const float*)d_in[23];
    const float* cr_n2g = (const float*)d_in[24];
    const float* cr_n2b = (const float*)d_in[25];
    const float* cr_f1w = (const float*)d_in[26];
    const float* cr_f1b = (const float*)d_in[27];
    const float* cr_f2w = (const float*)d_in[28];
    const float* cr_f2b = (const float*)d_in[29];
    const float* dconvw = (const float*)d_in[30];
    const float* ds_ng  = (const float*)d_in[31];
    const float* ds_nb  = (const float*)d_in[32];

    // workspace arena (all f32):
    float* ws   = (float*)d_ws;
    float* xb   = ws;                       // [NPIX,128] current x
    float* xcb  = xb  + (size_t)NPIX * CH;  // [NPIX,128] current x_cross
    float* xm   = xcb + (size_t)NPIX * CH;  // [NPIX,128] x_multi (unused copy target kept for layout)
    float* hn   = xm  + (size_t)NPIX * CH;  // [NPIX,128] LN scratch / conv out
    float* bufQ = hn  + (size_t)NPIX * CH;  // [NPIX,128] cross q
    float* attn = bufQ+ (size_t)NPIX * CH;  // [NPIX,128] NA out
    float* big  = attn+ (size_t)NPIX * CH;  // [NPIX,512] qkv / kv / fc1

    const int n4 = NPIX * CH / 4;
    dup_kernel<<<(n4 + 255) / 256, 256, 0, stream>>>(X, xb, xcb, n4);

    // ---- self-attention layers ----
    for (int l = 0; l < 2; ++l) {
        ln128_kernel<<<NPIX, 64, 0, stream>>>(xb, sa_n1g + l * CH, sa_n1b + l * CH, hn);
        gemm_kernel<<<dim3(NPIX / 64, 384 / 64), 256, 0, stream>>>(
            hn, sa_qkvw + (size_t)l * CH * 384, sa_qkvb + l * 384, nullptr, big,
            NPIX, 384, CH, 0);
        na_kernel<<<NPIX, 256, 0, stream>>>(big, 384, big + 128, big + 256, 384,
                                            sa_rpb + l * HEADS * 169, attn);
        gemm_kernel<<<dim3(NPIX / 64, 2), 256, 0, stream>>>(
            attn, sa_pw + (size_t)l * CH * CH, sa_pb + l * CH, xb, xb,
            NPIX, CH, CH, 2);
        ln128_kernel<<<NPIX, 64, 0, stream>>>(xb, sa_n2g + l * CH, sa_n2b + l * CH, hn);
        gemm_kernel<<<dim3(NPIX / 64, HID / 64), 256, 0, stream>>>(
            hn, sa_f1w + (size_t)l * CH * HID, sa_f1b + l * HID, nullptr, big,
            NPIX, HID, CH, 1);
        gemm_kernel<<<dim3(NPIX / 64, 2), 256, 0, stream>>>(
            big, sa_f2w + (size_t)l * HID * CH, sa_f2b + l * CH, xb, xb,
            NPIX, CH, HID, 2);
    }

    // ---- cross layers ----
    for (int l = 0; l < 2; ++l) {
        ln128_kernel<<<NPIX, 64, 0, stream>>>(XM, cr_n1g + l * CH, cr_n1b + l * CH, hn);
        gemm_kernel<<<dim3(NPIX / 64, 2), 256, 0, stream>>>(
            xcb, cr_qw + (size_t)l * CH * CH, cr_qb + l * CH, nullptr, bufQ,
            NPIX, CH, CH, 0);
        gemm_kernel<<<dim3(NPIX / 64, 4), 256, 0, stream>>>(
            hn, cr_kvw + (size_t)l * CH * 256, cr_kvb + l * 256, nullptr, big,
            NPIX, 256, CH, 0);
        na_kernel<<<NPIX, 256, 0, stream>>>(bufQ, 128, big, big + 128, 256,
                                            cr_rpb + l * HEADS * 169, attn);
        gemm_kernel<<<dim3(NPIX / 64, 2), 256, 0, stream>>>(
            attn, cr_pw + (size_t)l * CH * CH, cr_pb + l * CH, XM, xcb,
            NPIX, CH, CH, 2);
        ln128_kernel<<<NPIX, 64, 0, stream>>>(xcb, cr_n2g + l * CH, cr_n2b + l * CH, hn);
        gemm_kernel<<<dim3(NPIX / 64, HID / 64), 256, 0, stream>>>(
            hn, cr_f1w + (size_t)l * CH * HID, cr_f1b + l * HID, nullptr, big,
            NPIX, HID, CH, 1);
        gemm_kernel<<<dim3(NPIX / 64, 2), 256, 0, stream>>>(
            big, cr_f2w + (size_t)l * HID * CH, cr_f2b + l * CH, xcb, xcb,
            NPIX, CH, HID, 2);
    }

    // ---- downsample conv + final LN ----
    conv_kernel<<<3136, 256, 0, stream>>>(xb, xcb, dconvw, hn);
    ln512_out_kernel<<<3136, 64, 0, stream>>>(hn, ds_ng, ds_nb, (float*)d_out);
}

// Round 3
// 1046.237 us; speedup vs baseline: 1.5886x; 1.5886x over previous
//
#include <hip/hip_runtime.h>
#include <math.h>

#define NPIX 12544   // B*H*W = 4*56*56
#define CH   128
#define HEADS 4
#define HD   32
#define KS   7
#define HID  512
#define HH   56
#define WW   56

__device__ inline float gelu_f(float x) { return 0.5f * x * (1.0f + erff(x * 0.70710678118654752f)); }

// ---------------- copy f32 (duplicated into two state buffers) ----------------
__global__ __launch_bounds__(256) void dup_kernel(const float* __restrict__ in,
    float* __restrict__ o1, float* __restrict__ o2, int n4)
{
    int i = blockIdx.x * 256 + threadIdx.x;
    if (i < n4) {
        float4 v = reinterpret_cast<const float4*>(in)[i];
        reinterpret_cast<float4*>(o1)[i] = v;
        if (o2) reinterpret_cast<float4*>(o2)[i] = v;
    }
}

// ---------------- LayerNorm over C=128, one wave per row ----------------
__global__ __launch_bounds__(64) void ln128_kernel(const float* __restrict__ in,
    const float* __restrict__ g, const float* __restrict__ b, float* __restrict__ out)
{
    int p = blockIdx.x, lane = threadIdx.x;
    float2 v = reinterpret_cast<const float2*>(in + (size_t)p * CH)[lane];
    float s = v.x + v.y, sq = v.x * v.x + v.y * v.y;
#pragma unroll
    for (int o = 32; o > 0; o >>= 1) { s += __shfl_xor(s, o); sq += __shfl_xor(sq, o); }
    float mean = s * (1.0f / CH);
    float inv = rsqrtf(sq * (1.0f / CH) - mean * mean + 1e-5f);
    float2 gg = reinterpret_cast<const float2*>(g)[lane];
    float2 bb = reinterpret_cast<const float2*>(b)[lane];
    float2 o;
    o.x = (v.x - mean) * inv * gg.x + bb.x;
    o.y = (v.y - mean) * inv * gg.y + bb.y;
    reinterpret_cast<float2*>(out + (size_t)p * CH)[lane] = o;
}

// ---------------- Tiled GEMM: A[M,K] f32 x B[K,N] f32 -> C[M,N] f32 ----------------
// mode 0: +bias ; mode 1: gelu(+bias) ; mode 2: +bias + res
__global__ __launch_bounds__(256) void gemm_kernel(
    const float* __restrict__ A, const float* __restrict__ Bw,
    const float* __restrict__ bias, const float* __restrict__ res,
    float* __restrict__ C, int M, int N, int K, int mode)
{
    __shared__ float As[64][17];
    __shared__ float Bs[16][68];
    int t = threadIdx.x;
    int m0 = blockIdx.x * 64, n0 = blockIdx.y * 64;
    int tx = t & 15, ty = t >> 4;
    int ar = t >> 2, ac = (t & 3) * 4;
    int br = t >> 4, bc = (t & 15) * 4;
    float acc[4][4] = {};
    for (int k0 = 0; k0 < K; k0 += 16) {
        float4 av = *reinterpret_cast<const float4*>(A + (size_t)(m0 + ar) * K + k0 + ac);
        As[ar][ac + 0] = av.x; As[ar][ac + 1] = av.y; As[ar][ac + 2] = av.z; As[ar][ac + 3] = av.w;
        float4 bv = *reinterpret_cast<const float4*>(Bw + (size_t)(k0 + br) * N + n0 + bc);
        Bs[br][bc + 0] = bv.x; Bs[br][bc + 1] = bv.y;
        Bs[br][bc + 2] = bv.z; Bs[br][bc + 3] = bv.w;
        __syncthreads();
#pragma unroll
        for (int kk = 0; kk < 16; ++kk) {
            float a[4], bb[4];
#pragma unroll
            for (int i2 = 0; i2 < 4; ++i2) a[i2] = As[ty * 4 + i2][kk];
#pragma unroll
            for (int j2 = 0; j2 < 4; ++j2) bb[j2] = Bs[kk][tx * 4 + j2];
#pragma unroll
            for (int i2 = 0; i2 < 4; ++i2)
#pragma unroll
                for (int j2 = 0; j2 < 4; ++j2) acc[i2][j2] += a[i2] * bb[j2];
        }
        __syncthreads();
    }
#pragma unroll
    for (int i2 = 0; i2 < 4; ++i2) {
        int row = m0 + ty * 4 + i2;
#pragma unroll
        for (int j2 = 0; j2 < 4; ++j2) {
            int col = n0 + tx * 4 + j2;
            float v = acc[i2][j2] + bias[col];
            if (mode == 1) v = gelu_f(v);
            else if (mode == 2) v += res[(size_t)row * N + col];
            C[(size_t)row * N + col] = v;
        }
    }
}

// ---------------- Neighborhood attention: 1 block/pixel, 1 wave/head ----------------
__global__ __launch_bounds__(256) void na_kernel(
    const float* __restrict__ Q, int qld,
    const float* __restrict__ Kx, const float* __restrict__ Vx, int kvld,
    const float* __restrict__ rpb, float* __restrict__ Out)
{
    __shared__ float qs[HEADS][HD];
    __shared__ float as_[HEADS][64];
    __shared__ int pns[HEADS][49];
    int p = blockIdx.x;
    int bidx = p / (HH * WW); int rem = p % (HH * WW);
    int i = rem / WW, j = rem % WW;
    int h = threadIdx.x >> 6, lane = threadIdx.x & 63;

    if (lane < HD) qs[h][lane] = Q[(size_t)p * qld + h * HD + lane];
    int si = min(max(i - 3, 0), HH - KS), sj = min(max(j - 3, 0), WW - KS);
    int pn = 0, ri = 0, rj = 0;
    if (lane < 49) {
        int ai = lane / 7, aj = lane - ai * 7;
        int ni = si + ai, nj = sj + aj;
        pn = (bidx * HH + ni) * WW + nj;
        pns[h][lane] = pn;
        ri = ni - i + 6; rj = nj - j + 6;
    }
    __syncthreads();
    float s = -1e30f;
    if (lane < 49) {
        const float* kp = Kx + (size_t)pn * kvld + h * HD;
        float dot = 0.f;
#pragma unroll
        for (int d = 0; d < HD; ++d) dot += qs[h][d] * kp[d];
        s = dot * 0.17677669529663687f + rpb[h * 169 + ri * 13 + rj];
    }
    float m = s;
#pragma unroll
    for (int o = 32; o > 0; o >>= 1) m = fmaxf(m, __shfl_xor(m, o));
    float e = (lane < 49) ? expf(s - m) : 0.f;
    float sum = e;
#pragma unroll
    for (int o = 32; o > 0; o >>= 1) sum += __shfl_xor(sum, o);
    as_[h][lane] = e / sum;
    __syncthreads();
    if (lane < HD) {
        float o = 0.f;
        for (int mm = 0; mm < 49; ++mm)
            o += as_[h][mm] * Vx[(size_t)pns[h][mm] * kvld + h * HD + lane];
        Out[(size_t)p * CH + h * HD + lane] = o;
    }
}

// ---------------- conv as implicit GEMM ----------------
// M = 3136 output pixels (4x28x28), N = 512 out channels, K = 2304 (3x3x256).
// A[pm][k] gathered on the fly from X1/X2 (concat halves); B = Wt flat [K][512].
__global__ __launch_bounds__(256) void conv_gemm_kernel(
    const float* __restrict__ X1, const float* __restrict__ X2,
    const float* __restrict__ Wt, float* __restrict__ Out)
{
    __shared__ float As[64][17];
    __shared__ float Bs[16][68];
    int t = threadIdx.x;
    int m0 = blockIdx.x * 64, n0 = blockIdx.y * 64;
    int tx = t & 15, ty = t >> 4;
    int ar = t >> 2, ac = (t & 3) * 4;
    int br = t >> 4, bc = (t & 15) * 4;

    // decode this thread's A-row (output pixel) once
    int pm = m0 + ar;
    int b = pm / 784; int rem = pm % 784;
    int oi = rem / 28, oj = rem % 28;
    int ibase = 2 * oi - 1, jbase = 2 * oj - 1;

    float acc[4][4] = {};
    for (int k0 = 0; k0 < 2304; k0 += 16) {
        // ---- A gather: k = k0 + ac .. +3 (all within one tap, one concat half)
        int k = k0 + ac;
        int tap = k >> 8;                 // 0..8
        int ch = k & 255;
        int ky = tap / 3, kx = tap - ky * 3;
        int ii = ibase + ky, jj = jbase + kx;
        float4 av = make_float4(0.f, 0.f, 0.f, 0.f);
        if ((unsigned)ii < 56u && (unsigned)jj < 56u) {
            const float* src = (ch < 128) ? X1 : X2;
            size_t off = ((size_t)((b * 56 + ii) * 56 + jj)) * 128 + (ch & 127);
            av = *reinterpret_cast<const float4*>(src + off);
        }
        As[ar][ac + 0] = av.x; As[ar][ac + 1] = av.y; As[ar][ac + 2] = av.z; As[ar][ac + 3] = av.w;
        // ---- B load: weights flat [k][oc]
        float4 bv = *reinterpret_cast<const float4*>(Wt + (size_t)(k0 + br) * 512 + n0 + bc);
        Bs[br][bc + 0] = bv.x; Bs[br][bc + 1] = bv.y;
        Bs[br][bc + 2] = bv.z; Bs[br][bc + 3] = bv.w;
        __syncthreads();
#pragma unroll
        for (int kk = 0; kk < 16; ++kk) {
            float a[4], bb[4];
#pragma unroll
            for (int i2 = 0; i2 < 4; ++i2) a[i2] = As[ty * 4 + i2][kk];
#pragma unroll
            for (int j2 = 0; j2 < 4; ++j2) bb[j2] = Bs[kk][tx * 4 + j2];
#pragma unroll
            for (int i2 = 0; i2 < 4; ++i2)
#pragma unroll
                for (int j2 = 0; j2 < 4; ++j2) acc[i2][j2] += a[i2] * bb[j2];
        }
        __syncthreads();
    }
#pragma unroll
    for (int i2 = 0; i2 < 4; ++i2) {
        int row = m0 + ty * 4 + i2;
#pragma unroll
        for (int j2 = 0; j2 < 4; ++j2) {
            int col = n0 + tx * 4 + j2;
            Out[(size_t)row * 512 + col] = acc[i2][j2];
        }
    }
}

// ---------------- final LayerNorm over 512, write f32 ----------------
__global__ __launch_bounds__(64) void ln512_out_kernel(const float* __restrict__ in,
    const float* __restrict__ g, const float* __restrict__ b, float* __restrict__ out)
{
    int p = blockIdx.x, lane = threadIdx.x;
    const float4* ip = reinterpret_cast<const float4*>(in + (size_t)p * 512);
    float4 v0 = ip[lane * 2], v1 = ip[lane * 2 + 1];
    float vals[8] = { v0.x, v0.y, v0.z, v0.w, v1.x, v1.y, v1.z, v1.w };
    float s = 0.f, sq = 0.f;
#pragma unroll
    for (int q = 0; q < 8; ++q) { s += vals[q]; sq += vals[q] * vals[q]; }
#pragma unroll
    for (int o = 32; o > 0; o >>= 1) { s += __shfl_xor(s, o); sq += __shfl_xor(sq, o); }
    float mean = s * (1.0f / 512.0f);
    float inv = rsqrtf(sq * (1.0f / 512.0f) - mean * mean + 1e-5f);
#pragma unroll
    for (int q = 0; q < 8; ++q) {
        int c = lane * 8 + q;
        out[(size_t)p * 512 + c] = (vals[q] - mean) * inv * g[c] + b[c];
    }
}

extern "C" void kernel_launch(void* const* d_in, const int* in_sizes, int n_in,
                              void* d_out, int out_size, void* d_ws, size_t ws_size,
                              hipStream_t stream)
{
    const float* X      = (const float*)d_in[0];
    const float* XM     = (const float*)d_in[1];
    const float* sa_n1g = (const float*)d_in[2];
    const float* sa_n1b = (const float*)d_in[3];
    const float* sa_qkvw= (const float*)d_in[4];
    const float* sa_qkvb= (const float*)d_in[5];
    const float* sa_rpb = (const float*)d_in[6];
    const float* sa_pw  = (const float*)d_in[7];
    const float* sa_pb  = (const float*)d_in[8];
    const float* sa_n2g = (const float*)d_in[9];
    const float* sa_n2b = (const float*)d_in[10];
    const float* sa_f1w = (const float*)d_in[11];
    const float* sa_f1b = (const float*)d_in[12];
    const float* sa_f2w = (const float*)d_in[13];
    const float* sa_f2b = (const float*)d_in[14];
    const float* cr_n1g = (const float*)d_in[15];
    const float* cr_n1b = (const float*)d_in[16];
    const float* cr_qw  = (const float*)d_in[17];
    const float* cr_qb  = (const float*)d_in[18];
    const float* cr_kvw = (const float*)d_in[19];
    const float* cr_kvb = (const float*)d_in[20];
    const float* cr_rpb = (const float*)d_in[21];
    const float* cr_pw  = (const float*)d_in[22];
    const float* cr_pb  = (const float*)d_in[23];
    const float* cr_n2g = (const float*)d_in[24];
    const float* cr_n2b = (const float*)d_in[25];
    const float* cr_f1w = (const float*)d_in[26];
    const float* cr_f1b = (const float*)d_in[27];
    const float* cr_f2w = (const float*)d_in[28];
    const float* cr_f2b = (const float*)d_in[29];
    const float* dconvw = (const float*)d_in[30];
    const float* ds_ng  = (const float*)d_in[31];
    const float* ds_nb  = (const float*)d_in[32];

    // workspace arena (all f32):
    float* ws   = (float*)d_ws;
    float* xb   = ws;                       // [NPIX,128] current x
    float* xcb  = xb  + (size_t)NPIX * CH;  // [NPIX,128] current x_cross
    float* xm   = xcb + (size_t)NPIX * CH;  // [NPIX,128] (reserved)
    float* hn   = xm  + (size_t)NPIX * CH;  // [NPIX,128] LN scratch
    float* bufQ = hn  + (size_t)NPIX * CH;  // [NPIX,128] cross q
    float* attn = bufQ+ (size_t)NPIX * CH;  // [NPIX,128] NA out
    float* big  = attn+ (size_t)NPIX * CH;  // [NPIX,512] qkv / kv / fc1 / conv out

    const int n4 = NPIX * CH / 4;
    dup_kernel<<<(n4 + 255) / 256, 256, 0, stream>>>(X, xb, xcb, n4);

    // ---- self-attention layers ----
    for (int l = 0; l < 2; ++l) {
        ln128_kernel<<<NPIX, 64, 0, stream>>>(xb, sa_n1g + l * CH, sa_n1b + l * CH, hn);
        gemm_kernel<<<dim3(NPIX / 64, 384 / 64), 256, 0, stream>>>(
            hn, sa_qkvw + (size_t)l * CH * 384, sa_qkvb + l * 384, nullptr, big,
            NPIX, 384, CH, 0);
        na_kernel<<<NPIX, 256, 0, stream>>>(big, 384, big + 128, big + 256, 384,
                                            sa_rpb + l * HEADS * 169, attn);
        gemm_kernel<<<dim3(NPIX / 64, 2), 256, 0, stream>>>(
            attn, sa_pw + (size_t)l * CH * CH, sa_pb + l * CH, xb, xb,
            NPIX, CH, CH, 2);
        ln128_kernel<<<NPIX, 64, 0, stream>>>(xb, sa_n2g + l * CH, sa_n2b + l * CH, hn);
        gemm_kernel<<<dim3(NPIX / 64, HID / 64), 256, 0, stream>>>(
            hn, sa_f1w + (size_t)l * CH * HID, sa_f1b + l * HID, nullptr, big,
            NPIX, HID, CH, 1);
        gemm_kernel<<<dim3(NPIX / 64, 2), 256, 0, stream>>>(
            big, sa_f2w + (size_t)l * HID * CH, sa_f2b + l * CH, xb, xb,
            NPIX, CH, HID, 2);
    }

    // ---- cross layers ----
    for (int l = 0; l < 2; ++l) {
        ln128_kernel<<<NPIX, 64, 0, stream>>>(XM, cr_n1g + l * CH, cr_n1b + l * CH, hn);
        gemm_kernel<<<dim3(NPIX / 64, 2), 256, 0, stream>>>(
            xcb, cr_qw + (size_t)l * CH * CH, cr_qb + l * CH, nullptr, bufQ,
            NPIX, CH, CH, 0);
        gemm_kernel<<<dim3(NPIX / 64, 4), 256, 0, stream>>>(
            hn, cr_kvw + (size_t)l * CH * 256, cr_kvb + l * 256, nullptr, big,
            NPIX, 256, CH, 0);
        na_kernel<<<NPIX, 256, 0, stream>>>(bufQ, 128, big, big + 128, 256,
                                            cr_rpb + l * HEADS * 169, attn);
        gemm_kernel<<<dim3(NPIX / 64, 2), 256, 0, stream>>>(
            attn, cr_pw + (size_t)l * CH * CH, cr_pb + l * CH, XM, xcb,
            NPIX, CH, CH, 2);
        ln128_kernel<<<NPIX, 64, 0, stream>>>(xcb, cr_n2g + l * CH, cr_n2b + l * CH, hn);
        gemm_kernel<<<dim3(NPIX / 64, HID / 64), 256, 0, stream>>>(
            hn, cr_f1w + (size_t)l * CH * HID, cr_f1b + l * HID, nullptr, big,
            NPIX, HID, CH, 1);
        gemm_kernel<<<dim3(NPIX / 64, 2), 256, 0, stream>>>(
            big, cr_f2w + (size_t)l * HID * CH, cr_f2b + l * CH, xcb, xcb,
            NPIX, CH, HID, 2);
    }

    // ---- downsample conv (implicit GEMM) + final LN ----
    conv_gemm_kernel<<<dim3(3136 / 64, 512 / 64), 256, 0, stream>>>(xb, xcb, dconvw, big);
    ln512_out_kernel<<<3136, 64, 0, stream>>>(big, ds_ng, ds_nb, (float*)d_out);
}

// Round 4
// 608.721 us; speedup vs baseline: 2.7305x; 1.7187x over previous
//
#include <hip/hip_runtime.h>
#include <math.h>

#define NPIX 12544   // B*H*W = 4*56*56
#define CH   128
#define HEADS 4
#define HD   32
#define KS   7
#define HID  512
#define HH   56
#define WW   56

typedef __attribute__((ext_vector_type(8))) short bf16x8;
typedef __attribute__((ext_vector_type(4))) float f32x4;

__device__ inline float gelu_f(float x) { return 0.5f * x * (1.0f + erff(x * 0.70710678118654752f)); }

__device__ inline unsigned short rne_bf16(float x) {
    unsigned u = __float_as_uint(x);
    return (unsigned short)((u + 0x7fffu + ((u >> 16) & 1u)) >> 16);
}

// ---------------- copy f32 (duplicated into two state buffers) ----------------
__global__ __launch_bounds__(256) void dup_kernel(const float* __restrict__ in,
    float* __restrict__ o1, float* __restrict__ o2, int n4)
{
    int i = blockIdx.x * 256 + threadIdx.x;
    if (i < n4) {
        float4 v = reinterpret_cast<const float4*>(in)[i];
        reinterpret_cast<float4*>(o1)[i] = v;
        reinterpret_cast<float4*>(o2)[i] = v;
    }
}

// ---------------- f32 -> bf16 elementwise ----------------
__global__ __launch_bounds__(256) void cvtb_kernel(const float* __restrict__ in,
    unsigned short* __restrict__ out, int n4)
{
    int i = blockIdx.x * 256 + threadIdx.x;
    if (i < n4) {
        float4 v = reinterpret_cast<const float4*>(in)[i];
        ushort4 o;
        o.x = rne_bf16(v.x); o.y = rne_bf16(v.y); o.z = rne_bf16(v.z); o.w = rne_bf16(v.w);
        reinterpret_cast<ushort4*>(out)[i] = o;
    }
}

// ---------------- weight transpose + convert: f32 [K][N] -> bf16 [N][K] ----------------
struct TDesc { const float* src; unsigned short* dst; int K; int N; int tile0; };
struct TPack { TDesc d[19]; };

__global__ __launch_bounds__(256) void wtrans_kernel(TPack p)
{
    __shared__ float tl[32][33];
    int tile = blockIdx.x;
    int i = 0;
#pragma unroll 1
    while (i < 18 && tile >= p.d[i + 1].tile0) ++i;
    TDesc d = p.d[i];
    int local = tile - d.tile0;
    int ktiles = d.K >> 5;
    int lk = local % ktiles, ln_ = local / ktiles;
    int k0 = lk * 32, n0 = ln_ * 32;
    int tx = threadIdx.x & 31, ty = threadIdx.x >> 5;
#pragma unroll
    for (int r = 0; r < 4; ++r) {
        int row = ty * 4 + r;
        tl[row][tx] = d.src[(size_t)(k0 + row) * d.N + n0 + tx];
    }
    __syncthreads();
#pragma unroll
    for (int r = 0; r < 4; ++r) {
        int row = ty * 4 + r;
        d.dst[(size_t)(n0 + row) * d.K + k0 + tx] = rne_bf16(tl[tx][row]);
    }
}

// ---------------- LayerNorm over C=128, one wave per row, bf16 out ----------------
__global__ __launch_bounds__(64) void ln128_kernel(const float* __restrict__ in,
    const float* __restrict__ g, const float* __restrict__ b, unsigned short* __restrict__ out)
{
    int p = blockIdx.x, lane = threadIdx.x;
    float2 v = reinterpret_cast<const float2*>(in + (size_t)p * CH)[lane];
    float s = v.x + v.y, sq = v.x * v.x + v.y * v.y;
#pragma unroll
    for (int o = 32; o > 0; o >>= 1) { s += __shfl_xor(s, o); sq += __shfl_xor(sq, o); }
    float mean = s * (1.0f / CH);
    float inv = rsqrtf(sq * (1.0f / CH) - mean * mean + 1e-5f);
    float2 gg = reinterpret_cast<const float2*>(g)[lane];
    float2 bb = reinterpret_cast<const float2*>(b)[lane];
    ushort2 o;
    o.x = rne_bf16((v.x - mean) * inv * gg.x + bb.x);
    o.y = rne_bf16((v.y - mean) * inv * gg.y + bb.y);
    reinterpret_cast<ushort2*>(out + (size_t)p * CH)[lane] = o;
}

// ---------------- MFMA GEMM: A bf16 [M][K], Bt bf16 [N][K] -> C [M][N] ----------------
// MODE 0: f32 = acc+bias ; MODE 1: bf16 = gelu(acc+bias) ; MODE 2: f32 = acc+bias+res
template<int BN, int MODE>
__global__ __launch_bounds__(256) void mfma_gemm_kernel(
    const unsigned short* __restrict__ A, const unsigned short* __restrict__ Bt,
    const float* __restrict__ bias, const float* __restrict__ res,
    float* __restrict__ Cf, unsigned short* __restrict__ Cb,
    int M, int N, int K)
{
    constexpr int MF = 4, NF = BN / 32;
    __shared__ unsigned short Als[128 * 64];
    __shared__ unsigned short Bls[BN * 64];
    char* alsb = reinterpret_cast<char*>(Als);
    char* blsb = reinterpret_cast<char*>(Bls);
    int t = threadIdx.x;
    int m0 = blockIdx.x * 128, n0 = blockIdx.y * BN;
    int lane = t & 63, w = t >> 6;
    int wr = w >> 1, wc = w & 1;
    f32x4 acc[MF][NF] = {};
    for (int k0 = 0; k0 < K; k0 += 64) {
#pragma unroll
        for (int i = 0; i < 4; ++i) {
            int s = t + i * 256, row = s >> 3, ch = (s & 7) * 8;
            bf16x8 v = *reinterpret_cast<const bf16x8*>(A + (size_t)(m0 + row) * K + k0 + ch);
            *reinterpret_cast<bf16x8*>(alsb + row * 128 + ((ch * 2) ^ ((row & 7) << 4))) = v;
        }
#pragma unroll
        for (int i = 0; i < NF; ++i) {
            int s = t + i * 256, row = s >> 3, ch = (s & 7) * 8;
            bf16x8 v = *reinterpret_cast<const bf16x8*>(Bt + (size_t)(n0 + row) * K + k0 + ch);
            *reinterpret_cast<bf16x8*>(blsb + row * 128 + ((ch * 2) ^ ((row & 7) << 4))) = v;
        }
        __syncthreads();
#pragma unroll
        for (int kk = 0; kk < 2; ++kk) {
            int kb = kk * 64 + (lane >> 4) * 16;
            bf16x8 af[MF], bfr[NF];
#pragma unroll
            for (int mi = 0; mi < MF; ++mi) {
                int row = wr * 64 + mi * 16 + (lane & 15);
                af[mi] = *reinterpret_cast<const bf16x8*>(alsb + row * 128 + (kb ^ ((row & 7) << 4)));
            }
#pragma unroll
            for (int ni = 0; ni < NF; ++ni) {
                int row = wc * (BN / 2) + ni * 16 + (lane & 15);
                bfr[ni] = *reinterpret_cast<const bf16x8*>(blsb + row * 128 + (kb ^ ((row & 7) << 4)));
            }
#pragma unroll
            for (int mi = 0; mi < MF; ++mi)
#pragma unroll
                for (int ni = 0; ni < NF; ++ni)
                    acc[mi][ni] = __builtin_amdgcn_mfma_f32_16x16x32_bf16(af[mi], bfr[ni], acc[mi][ni], 0, 0, 0);
        }
        __syncthreads();
    }
    int fq = lane >> 4, fr = lane & 15;
#pragma unroll
    for (int mi = 0; mi < MF; ++mi) {
#pragma unroll
        for (int ni = 0; ni < NF; ++ni) {
            int col = n0 + wc * (BN / 2) + ni * 16 + fr;
            float bv = bias[col];
#pragma unroll
            for (int j = 0; j < 4; ++j) {
                int row = m0 + wr * 64 + mi * 16 + fq * 4 + j;
                float v = acc[mi][ni][j] + bv;
                if constexpr (MODE == 1) {
                    Cb[(size_t)row * N + col] = rne_bf16(gelu_f(v));
                } else if constexpr (MODE == 2) {
                    Cf[(size_t)row * N + col] = v + res[(size_t)row * N + col];
                } else {
                    Cf[(size_t)row * N + col] = v;
                }
            }
        }
    }
}

// ---------------- conv as MFMA implicit GEMM: M=3136 (BM=64), N=512 (BN=128), K=2304 ----------------
__global__ __launch_bounds__(256) void conv_mfma_kernel(
    const unsigned short* __restrict__ Xb, const unsigned short* __restrict__ Xc,
    const unsigned short* __restrict__ Wt, float* __restrict__ Out)
{
    __shared__ unsigned short Als[64 * 64];
    __shared__ unsigned short Bls[128 * 64];
    char* alsb = reinterpret_cast<char*>(Als);
    char* blsb = reinterpret_cast<char*>(Bls);
    int t = threadIdx.x;
    int m0 = blockIdx.x * 64, n0 = blockIdx.y * 128;
    int lane = t & 63, w = t >> 6, wr = w >> 1, wc = w & 1;

    // precompute pixel decode for the 2 A-staging slots (constant across k-loop)
    int rowi[2], chv[2], pb[2], ib[2], jb[2];
#pragma unroll
    for (int i = 0; i < 2; ++i) {
        int s = t + i * 256;
        rowi[i] = s >> 3; chv[i] = (s & 7) * 8;
        int pm = m0 + rowi[i];
        int b = pm / 784; int rem = pm - b * 784;
        int oi = rem / 28, oj = rem - oi * 28;
        pb[i] = b * 56; ib[i] = 2 * oi - 1; jb[i] = 2 * oj - 1;
    }
    f32x4 acc[2][4] = {};
    for (int k0 = 0; k0 < 2304; k0 += 64) {
#pragma unroll
        for (int i = 0; i < 2; ++i) {
            int row = rowi[i];
            int k = k0 + chv[i];
            int tap = k >> 8, c = k & 255;
            int ky = (tap * 11) >> 5, kx = tap - ky * 3;
            int ii = ib[i] + ky, jj = jb[i] + kx;
            bf16x8 v = {};
            if ((unsigned)ii < 56u && (unsigned)jj < 56u) {
                const unsigned short* src = (c < 128) ? Xb : Xc;
                v = *reinterpret_cast<const bf16x8*>(src + (size_t)((pb[i] + ii) * 56 + jj) * 128 + (c & 127));
            }
            *reinterpret_cast<bf16x8*>(alsb + row * 128 + ((chv[i] * 2) ^ ((row & 7) << 4))) = v;
        }
#pragma unroll
        for (int i = 0; i < 4; ++i) {
            int s = t + i * 256, row = s >> 3, ch = (s & 7) * 8;
            bf16x8 v = *reinterpret_cast<const bf16x8*>(Wt + (size_t)(n0 + row) * 2304 + k0 + ch);
            *reinterpret_cast<bf16x8*>(blsb + row * 128 + ((ch * 2) ^ ((row & 7) << 4))) = v;
        }
        __syncthreads();
#pragma unroll
        for (int kk = 0; kk < 2; ++kk) {
            int kb = kk * 64 + (lane >> 4) * 16;
            bf16x8 af[2], bfr[4];
#pragma unroll
            for (int mi = 0; mi < 2; ++mi) {
                int row = wr * 32 + mi * 16 + (lane & 15);
                af[mi] = *reinterpret_cast<const bf16x8*>(alsb + row * 128 + (kb ^ ((row & 7) << 4)));
            }
#pragma unroll
            for (int ni = 0; ni < 4; ++ni) {
                int row = wc * 64 + ni * 16 + (lane & 15);
                bfr[ni] = *reinterpret_cast<const bf16x8*>(blsb + row * 128 + (kb ^ ((row & 7) << 4)));
            }
#pragma unroll
            for (int mi = 0; mi < 2; ++mi)
#pragma unroll
                for (int ni = 0; ni < 4; ++ni)
                    acc[mi][ni] = __builtin_amdgcn_mfma_f32_16x16x32_bf16(af[mi], bfr[ni], acc[mi][ni], 0, 0, 0);
        }
        __syncthreads();
    }
    int fq = lane >> 4, fr = lane & 15;
#pragma unroll
    for (int mi = 0; mi < 2; ++mi)
#pragma unroll
        for (int ni = 0; ni < 4; ++ni) {
            int col = n0 + wc * 64 + ni * 16 + fr;
#pragma unroll
            for (int j = 0; j < 4; ++j) {
                int row = m0 + wr * 32 + mi * 16 + fq * 4 + j;
                Out[(size_t)row * 512 + col] = acc[mi][ni][j];
            }
        }
}

// ---------------- Neighborhood attention: 1 block/pixel, 1 wave/head, bf16 out ----------------
__global__ __launch_bounds__(256) void na_kernel(
    const float* __restrict__ Q, int qld,
    const float* __restrict__ Kx, const float* __restrict__ Vx, int kvld,
    const float* __restrict__ rpb, unsigned short* __restrict__ Out)
{
    __shared__ float qs[HEADS][HD];
    __shared__ float as_[HEADS][64];
    __shared__ int pns[HEADS][49];
    int p = blockIdx.x;
    int bidx = p / (HH * WW); int rem = p % (HH * WW);
    int i = rem / WW, j = rem % WW;
    int h = threadIdx.x >> 6, lane = threadIdx.x & 63;

    if (lane < HD) qs[h][lane] = Q[(size_t)p * qld + h * HD + lane];
    int si = min(max(i - 3, 0), HH - KS), sj = min(max(j - 3, 0), WW - KS);
    int pn = 0, ri = 0, rj = 0;
    if (lane < 49) {
        int ai = lane / 7, aj = lane - ai * 7;
        int ni = si + ai, nj = sj + aj;
        pn = (bidx * HH + ni) * WW + nj;
        pns[h][lane] = pn;
        ri = ni - i + 6; rj = nj - j + 6;
    }
    __syncthreads();
    float s = -1e30f;
    if (lane < 49) {
        const float* kp = Kx + (size_t)pn * kvld + h * HD;
        float dot = 0.f;
#pragma unroll
        for (int d = 0; d < HD; ++d) dot += qs[h][d] * kp[d];
        s = dot * 0.17677669529663687f + rpb[h * 169 + ri * 13 + rj];
    }
    float m = s;
#pragma unroll
    for (int o = 32; o > 0; o >>= 1) m = fmaxf(m, __shfl_xor(m, o));
    float e = (lane < 49) ? expf(s - m) : 0.f;
    float sum = e;
#pragma unroll
    for (int o = 32; o > 0; o >>= 1) sum += __shfl_xor(sum, o);
    as_[h][lane] = e / sum;
    __syncthreads();
    if (lane < HD) {
        float o = 0.f;
        for (int mm = 0; mm < 49; ++mm)
            o += as_[h][mm] * Vx[(size_t)pns[h][mm] * kvld + h * HD + lane];
        Out[(size_t)p * CH + h * HD + lane] = rne_bf16(o);
    }
}

// ---------------- final LayerNorm over 512, write f32 ----------------
__global__ __launch_bounds__(64) void ln512_out_kernel(const float* __restrict__ in,
    const float* __restrict__ g, const float* __restrict__ b, float* __restrict__ out)
{
    int p = blockIdx.x, lane = threadIdx.x;
    const float4* ip = reinterpret_cast<const float4*>(in + (size_t)p * 512);
    float4 v0 = ip[lane * 2], v1 = ip[lane * 2 + 1];
    float vals[8] = { v0.x, v0.y, v0.z, v0.w, v1.x, v1.y, v1.z, v1.w };
    float s = 0.f, sq = 0.f;
#pragma unroll
    for (int q = 0; q < 8; ++q) { s += vals[q]; sq += vals[q] * vals[q]; }
#pragma unroll
    for (int o = 32; o > 0; o >>= 1) { s += __shfl_xor(s, o); sq += __shfl_xor(sq, o); }
    float mean = s * (1.0f / 512.0f);
    float inv = rsqrtf(sq * (1.0f / 512.0f) - mean * mean + 1e-5f);
#pragma unroll
    for (int q = 0; q < 8; ++q) {
        int c = lane * 8 + q;
        out[(size_t)p * 512 + c] = (vals[q] - mean) * inv * g[c] + b[c];
    }
}

extern "C" void kernel_launch(void* const* d_in, const int* in_sizes, int n_in,
                              void* d_out, int out_size, void* d_ws, size_t ws_size,
                              hipStream_t stream)
{
    const float* X      = (const float*)d_in[0];
    const float* XM     = (const float*)d_in[1];
    const float* sa_n1g = (const float*)d_in[2];
    const float* sa_n1b = (const float*)d_in[3];
    const float* sa_qkvw= (const float*)d_in[4];
    const float* sa_qkvb= (const float*)d_in[5];
    const float* sa_rpb = (const float*)d_in[6];
    const float* sa_pw  = (const float*)d_in[7];
    const float* sa_pb  = (const float*)d_in[8];
    const float* sa_n2g = (const float*)d_in[9];
    const float* sa_n2b = (const float*)d_in[10];
    const float* sa_f1w = (const float*)d_in[11];
    const float* sa_f1b = (const float*)d_in[12];
    const float* sa_f2w = (const float*)d_in[13];
    const float* sa_f2b = (const float*)d_in[14];
    const float* cr_n1g = (const float*)d_in[15];
    const float* cr_n1b = (const float*)d_in[16];
    const float* cr_qw  = (const float*)d_in[17];
    const float* cr_qb  = (const float*)d_in[18];
    const float* cr_kvw = (const float*)d_in[19];
    const float* cr_kvb = (const float*)d_in[20];
    const float* cr_rpb = (const float*)d_in[21];
    const float* cr_pw  = (const float*)d_in[22];
    const float* cr_pb  = (const float*)d_in[23];
    const float* cr_n2g = (const float*)d_in[24];
    const float* cr_n2b = (const float*)d_in[25];
    const float* cr_f1w = (const float*)d_in[26];
    const float* cr_f1b = (const float*)d_in[27];
    const float* cr_f2w = (const float*)d_in[28];
    const float* cr_f2b = (const float*)d_in[29];
    const float* dconvw = (const float*)d_in[30];
    const float* ds_ng  = (const float*)d_in[31];
    const float* ds_nb  = (const float*)d_in[32];

    const size_t NC = (size_t)NPIX * CH;       // 1,605,632
    float* ws   = (float*)d_ws;
    float* xb   = ws;
    float* xcb  = xb + NC;
    float* bufQ = xcb + NC;
    float* big  = bufQ + NC;                   // [NPIX,512] f32
    unsigned short* hnb   = (unsigned short*)(big + (size_t)NPIX * 512);
    unsigned short* attnb = hnb + NC;
    unsigned short* xcbbf = attnb + NC;
    unsigned short* wa    = xcbbf + NC;        // bf16 weight arena (~2.0M elems)
    unsigned short* bigb  = (unsigned short*)big;  // alias: fc1 bf16 out (safe: qkv/kv dead by then)

    // ---- weight arena layout + transpose descriptors ----
    TPack tp;
    int tile = 0, idx = 0;
    unsigned short* p = wa;
    unsigned short* qkvt[2]; unsigned short* pwt[2]; unsigned short* f1t[2]; unsigned short* f2t[2];
    unsigned short* qt[2];   unsigned short* kvt[2]; unsigned short* cpt[2]; unsigned short* cf1t[2];
    unsigned short* cf2t[2]; unsigned short* convt;
    auto add = [&](const float* s, unsigned short*& dst, int K, int N) {
        dst = p;
        tp.d[idx].src = s; tp.d[idx].dst = p; tp.d[idx].K = K; tp.d[idx].N = N; tp.d[idx].tile0 = tile;
        tile += (K / 32) * (N / 32); p += (size_t)K * N; ++idx;
    };
    for (int l = 0; l < 2; ++l) add(sa_qkvw + (size_t)l * 128 * 384, qkvt[l], 128, 384);
    for (int l = 0; l < 2; ++l) add(sa_pw   + (size_t)l * 128 * 128, pwt[l],  128, 128);
    for (int l = 0; l < 2; ++l) add(sa_f1w  + (size_t)l * 128 * 512, f1t[l],  128, 512);
    for (int l = 0; l < 2; ++l) add(sa_f2w  + (size_t)l * 512 * 128, f2t[l],  512, 128);
    for (int l = 0; l < 2; ++l) add(cr_qw   + (size_t)l * 128 * 128, qt[l],   128, 128);
    for (int l = 0; l < 2; ++l) add(cr_kvw  + (size_t)l * 128 * 256, kvt[l],  128, 256);
    for (int l = 0; l < 2; ++l) add(cr_pw   + (size_t)l * 128 * 128, cpt[l],  128, 128);
    for (int l = 0; l < 2; ++l) add(cr_f1w  + (size_t)l * 128 * 512, cf1t[l], 128, 512);
    for (int l = 0; l < 2; ++l) add(cr_f2w  + (size_t)l * 512 * 128, cf2t[l], 512, 128);
    add(dconvw, convt, 2304, 512);

    wtrans_kernel<<<tile, 256, 0, stream>>>(tp);

    const int n4 = NPIX * CH / 4;
    dup_kernel<<<(n4 + 255) / 256, 256, 0, stream>>>(X, xb, xcb, n4);

    // ---- self-attention layers ----
    for (int l = 0; l < 2; ++l) {
        ln128_kernel<<<NPIX, 64, 0, stream>>>(xb, sa_n1g + l * CH, sa_n1b + l * CH, hnb);
        mfma_gemm_kernel<128, 0><<<dim3(NPIX / 128, 3), 256, 0, stream>>>(
            hnb, qkvt[l], sa_qkvb + l * 384, nullptr, big, nullptr, NPIX, 384, 128);
        na_kernel<<<NPIX, 256, 0, stream>>>(big, 384, big + 128, big + 256, 384,
                                            sa_rpb + l * HEADS * 169, attnb);
        mfma_gemm_kernel<64, 2><<<dim3(NPIX / 128, 2), 256, 0, stream>>>(
            attnb, pwt[l], sa_pb + l * CH, xb, xb, nullptr, NPIX, 128, 128);
        ln128_kernel<<<NPIX, 64, 0, stream>>>(xb, sa_n2g + l * CH, sa_n2b + l * CH, hnb);
        mfma_gemm_kernel<128, 1><<<dim3(NPIX / 128, 4), 256, 0, stream>>>(
            hnb, f1t[l], sa_f1b + l * HID, nullptr, nullptr, bigb, NPIX, 512, 128);
        mfma_gemm_kernel<64, 2><<<dim3(NPIX / 128, 2), 256, 0, stream>>>(
            bigb, f2t[l], sa_f2b + l * CH, xb, xb, nullptr, NPIX, 128, 512);
    }

    // ---- cross layers ----
    for (int l = 0; l < 2; ++l) {
        ln128_kernel<<<NPIX, 64, 0, stream>>>(XM, cr_n1g + l * CH, cr_n1b + l * CH, hnb);
        cvtb_kernel<<<(n4 + 255) / 256, 256, 0, stream>>>(xcb, xcbbf, n4);
        mfma_gemm_kernel<64, 0><<<dim3(NPIX / 128, 2), 256, 0, stream>>>(
            xcbbf, qt[l], cr_qb + l * CH, nullptr, bufQ, nullptr, NPIX, 128, 128);
        mfma_gemm_kernel<128, 0><<<dim3(NPIX / 128, 2), 256, 0, stream>>>(
            hnb, kvt[l], cr_kvb + l * 256, nullptr, big, nullptr, NPIX, 256, 128);
        na_kernel<<<NPIX, 256, 0, stream>>>(bufQ, 128, big, big + 128, 256,
                                            cr_rpb + l * HEADS * 169, attnb);
        mfma_gemm_kernel<64, 2><<<dim3(NPIX / 128, 2), 256, 0, stream>>>(
            attnb, cpt[l], cr_pb + l * CH, XM, xcb, nullptr, NPIX, 128, 128);
        ln128_kernel<<<NPIX, 64, 0, stream>>>(xcb, cr_n2g + l * CH, cr_n2b + l * CH, hnb);
        mfma_gemm_kernel<128, 1><<<dim3(NPIX / 128, 4), 256, 0, stream>>>(
            hnb, cf1t[l], cr_f1b + l * HID, nullptr, nullptr, bigb, NPIX, 512, 128);
        mfma_gemm_kernel<64, 2><<<dim3(NPIX / 128, 2), 256, 0, stream>>>(
            bigb, cf2t[l], cr_f2b + l * CH, xcb, xcb, nullptr, NPIX, 128, 512);
    }

    // ---- downsample conv (MFMA implicit GEMM) + final LN ----
    cvtb_kernel<<<(n4 + 255) / 256, 256, 0, stream>>>(xb, hnb, n4);
    cvtb_kernel<<<(n4 + 255) / 256, 256, 0, stream>>>(xcb, attnb, n4);
    conv_mfma_kernel<<<dim3(3136 / 64, 4), 256, 0, stream>>>(hnb, attnb, convt, big);
    ln512_out_kernel<<<3136, 64, 0, stream>>>(big, ds_ng, ds_nb, (float*)d_out);
}

// Round 5
// 522.940 us; speedup vs baseline: 3.1784x; 1.1640x over previous
//
#include <hip/hip_runtime.h>
#include <math.h>

#define NPIX 12544   // B*H*W = 4*56*56
#define CH   128
#define HEADS 4
#define HD   32
#define KS   7
#define HID  512
#define HH   56
#define WW   56

typedef __attribute__((ext_vector_type(8))) short bf16x8;
typedef __attribute__((ext_vector_type(4))) float f32x4;

__device__ inline float gelu_f(float x) { return 0.5f * x * (1.0f + erff(x * 0.70710678118654752f)); }

__device__ inline unsigned short rne_bf16(float x) {
    unsigned u = __float_as_uint(x);
    return (unsigned short)((u + 0x7fffu + ((u >> 16) & 1u)) >> 16);
}

// ---------------- copy f32 (duplicated into two state buffers) ----------------
__global__ __launch_bounds__(256) void dup_kernel(const float* __restrict__ in,
    float* __restrict__ o1, float* __restrict__ o2, int n4)
{
    int i = blockIdx.x * 256 + threadIdx.x;
    if (i < n4) {
        float4 v = reinterpret_cast<const float4*>(in)[i];
        reinterpret_cast<float4*>(o1)[i] = v;
        reinterpret_cast<float4*>(o2)[i] = v;
    }
}

// ---------------- f32 -> bf16 elementwise ----------------
__global__ __launch_bounds__(256) void cvtb_kernel(const float* __restrict__ in,
    unsigned short* __restrict__ out, int n4)
{
    int i = blockIdx.x * 256 + threadIdx.x;
    if (i < n4) {
        float4 v = reinterpret_cast<const float4*>(in)[i];
        ushort4 o;
        o.x = rne_bf16(v.x); o.y = rne_bf16(v.y); o.z = rne_bf16(v.z); o.w = rne_bf16(v.w);
        reinterpret_cast<ushort4*>(out)[i] = o;
    }
}

// ---------------- weight transpose + convert: f32 [K][N] -> bf16 [N][K] ----------------
struct TDesc { const float* src; unsigned short* dst; int K; int N; int tile0; };
struct TPack { TDesc d[19]; };

__global__ __launch_bounds__(256) void wtrans_kernel(TPack p)
{
    __shared__ float tl[32][33];
    int tile = blockIdx.x;
    int i = 0;
#pragma unroll 1
    while (i < 18 && tile >= p.d[i + 1].tile0) ++i;
    TDesc d = p.d[i];
    int local = tile - d.tile0;
    int ktiles = d.K >> 5;
    int lk = local % ktiles, ln_ = local / ktiles;
    int k0 = lk * 32, n0 = ln_ * 32;
    int tx = threadIdx.x & 31, ty = threadIdx.x >> 5;
#pragma unroll
    for (int r = 0; r < 4; ++r) {
        int row = ty * 4 + r;
        tl[row][tx] = d.src[(size_t)(k0 + row) * d.N + n0 + tx];
    }
    __syncthreads();
#pragma unroll
    for (int r = 0; r < 4; ++r) {
        int row = ty * 4 + r;
        d.dst[(size_t)(n0 + row) * d.K + k0 + tx] = rne_bf16(tl[tx][row]);
    }
}

// ---------------- LayerNorm over C=128, one wave per row, bf16 out ----------------
__global__ __launch_bounds__(64) void ln128_kernel(const float* __restrict__ in,
    const float* __restrict__ g, const float* __restrict__ b, unsigned short* __restrict__ out)
{
    int p = blockIdx.x, lane = threadIdx.x;
    float2 v = reinterpret_cast<const float2*>(in + (size_t)p * CH)[lane];
    float s = v.x + v.y, sq = v.x * v.x + v.y * v.y;
#pragma unroll
    for (int o = 32; o > 0; o >>= 1) { s += __shfl_xor(s, o); sq += __shfl_xor(sq, o); }
    float mean = s * (1.0f / CH);
    float inv = rsqrtf(sq * (1.0f / CH) - mean * mean + 1e-5f);
    float2 gg = reinterpret_cast<const float2*>(g)[lane];
    float2 bb = reinterpret_cast<const float2*>(b)[lane];
    ushort2 o;
    o.x = rne_bf16((v.x - mean) * inv * gg.x + bb.x);
    o.y = rne_bf16((v.y - mean) * inv * gg.y + bb.y);
    reinterpret_cast<ushort2*>(out + (size_t)p * CH)[lane] = o;
}

// ---------------- MFMA GEMM: A bf16 [M][K], Bt bf16 [N][K] -> C [M][N] ----------------
// MODE 0: f32 = acc+bias ; MODE 1: bf16 = gelu(acc+bias) ; MODE 2: f32 = acc+bias+res
template<int BN, int MODE>
__global__ __launch_bounds__(256) void mfma_gemm_kernel(
    const unsigned short* __restrict__ A, const unsigned short* __restrict__ Bt,
    const float* __restrict__ bias, const float* __restrict__ res,
    float* __restrict__ Cf, unsigned short* __restrict__ Cb,
    int M, int N, int K)
{
    constexpr int MF = 4, NF = BN / 32;
    __shared__ unsigned short Als[128 * 64];
    __shared__ unsigned short Bls[BN * 64];
    char* alsb = reinterpret_cast<char*>(Als);
    char* blsb = reinterpret_cast<char*>(Bls);
    int t = threadIdx.x;
    int m0 = blockIdx.x * 128, n0 = blockIdx.y * BN;
    int lane = t & 63, w = t >> 6;
    int wr = w >> 1, wc = w & 1;
    f32x4 acc[MF][NF] = {};
    for (int k0 = 0; k0 < K; k0 += 64) {
#pragma unroll
        for (int i = 0; i < 4; ++i) {
            int s = t + i * 256, row = s >> 3, ch = (s & 7) * 8;
            bf16x8 v = *reinterpret_cast<const bf16x8*>(A + (size_t)(m0 + row) * K + k0 + ch);
            *reinterpret_cast<bf16x8*>(alsb + row * 128 + ((ch * 2) ^ ((row & 7) << 4))) = v;
        }
#pragma unroll
        for (int i = 0; i < NF; ++i) {
            int s = t + i * 256, row = s >> 3, ch = (s & 7) * 8;
            bf16x8 v = *reinterpret_cast<const bf16x8*>(Bt + (size_t)(n0 + row) * K + k0 + ch);
            *reinterpret_cast<bf16x8*>(blsb + row * 128 + ((ch * 2) ^ ((row & 7) << 4))) = v;
        }
        __syncthreads();
#pragma unroll
        for (int kk = 0; kk < 2; ++kk) {
            int kb = kk * 64 + (lane >> 4) * 16;
            bf16x8 af[MF], bfr[NF];
#pragma unroll
            for (int mi = 0; mi < MF; ++mi) {
                int row = wr * 64 + mi * 16 + (lane & 15);
                af[mi] = *reinterpret_cast<const bf16x8*>(alsb + row * 128 + (kb ^ ((row & 7) << 4)));
            }
#pragma unroll
            for (int ni = 0; ni < NF; ++ni) {
                int row = wc * (BN / 2) + ni * 16 + (lane & 15);
                bfr[ni] = *reinterpret_cast<const bf16x8*>(blsb + row * 128 + (kb ^ ((row & 7) << 4)));
            }
#pragma unroll
            for (int mi = 0; mi < MF; ++mi)
#pragma unroll
                for (int ni = 0; ni < NF; ++ni)
                    acc[mi][ni] = __builtin_amdgcn_mfma_f32_16x16x32_bf16(af[mi], bfr[ni], acc[mi][ni], 0, 0, 0);
        }
        __syncthreads();
    }
    int fq = lane >> 4, fr = lane & 15;
#pragma unroll
    for (int mi = 0; mi < MF; ++mi) {
#pragma unroll
        for (int ni = 0; ni < NF; ++ni) {
            int col = n0 + wc * (BN / 2) + ni * 16 + fr;
            float bv = bias[col];
#pragma unroll
            for (int j = 0; j < 4; ++j) {
                int row = m0 + wr * 64 + mi * 16 + fq * 4 + j;
                float v = acc[mi][ni][j] + bv;
                if constexpr (MODE == 1) {
                    Cb[(size_t)row * N + col] = rne_bf16(gelu_f(v));
                } else if constexpr (MODE == 2) {
                    Cf[(size_t)row * N + col] = v + res[(size_t)row * N + col];
                } else {
                    Cf[(size_t)row * N + col] = v;
                }
            }
        }
    }
}

// ---------------- conv as MFMA implicit GEMM: M=3136 (BM=64), N=512 (BN=128), K=2304 ----------------
__global__ __launch_bounds__(256) void conv_mfma_kernel(
    const unsigned short* __restrict__ Xb, const unsigned short* __restrict__ Xc,
    const unsigned short* __restrict__ Wt, float* __restrict__ Out)
{
    __shared__ unsigned short Als[64 * 64];
    __shared__ unsigned short Bls[128 * 64];
    char* alsb = reinterpret_cast<char*>(Als);
    char* blsb = reinterpret_cast<char*>(Bls);
    int t = threadIdx.x;
    int m0 = blockIdx.x * 64, n0 = blockIdx.y * 128;
    int lane = t & 63, w = t >> 6, wr = w >> 1, wc = w & 1;

    int rowi[2], chv[2], pb[2], ib[2], jb[2];
#pragma unroll
    for (int i = 0; i < 2; ++i) {
        int s = t + i * 256;
        rowi[i] = s >> 3; chv[i] = (s & 7) * 8;
        int pm = m0 + rowi[i];
        int b = pm / 784; int rem = pm - b * 784;
        int oi = rem / 28, oj = rem - oi * 28;
        pb[i] = b * 56; ib[i] = 2 * oi - 1; jb[i] = 2 * oj - 1;
    }
    f32x4 acc[2][4] = {};
    for (int k0 = 0; k0 < 2304; k0 += 64) {
#pragma unroll
        for (int i = 0; i < 2; ++i) {
            int row = rowi[i];
            int k = k0 + chv[i];
            int tap = k >> 8, c = k & 255;
            int ky = (tap * 11) >> 5, kx = tap - ky * 3;
            int ii = ib[i] + ky, jj = jb[i] + kx;
            bf16x8 v = {};
            if ((unsigned)ii < 56u && (unsigned)jj < 56u) {
                const unsigned short* src = (c < 128) ? Xb : Xc;
                v = *reinterpret_cast<const bf16x8*>(src + (size_t)((pb[i] + ii) * 56 + jj) * 128 + (c & 127));
            }
            *reinterpret_cast<bf16x8*>(alsb + row * 128 + ((chv[i] * 2) ^ ((row & 7) << 4))) = v;
        }
#pragma unroll
        for (int i = 0; i < 4; ++i) {
            int s = t + i * 256, row = s >> 3, ch = (s & 7) * 8;
            bf16x8 v = *reinterpret_cast<const bf16x8*>(Wt + (size_t)(n0 + row) * 2304 + k0 + ch);
            *reinterpret_cast<bf16x8*>(blsb + row * 128 + ((ch * 2) ^ ((row & 7) << 4))) = v;
        }
        __syncthreads();
#pragma unroll
        for (int kk = 0; kk < 2; ++kk) {
            int kb = kk * 64 + (lane >> 4) * 16;
            bf16x8 af[2], bfr[4];
#pragma unroll
            for (int mi = 0; mi < 2; ++mi) {
                int row = wr * 32 + mi * 16 + (lane & 15);
                af[mi] = *reinterpret_cast<const bf16x8*>(alsb + row * 128 + (kb ^ ((row & 7) << 4)));
            }
#pragma unroll
            for (int ni = 0; ni < 4; ++ni) {
                int row = wc * 64 + ni * 16 + (lane & 15);
                bfr[ni] = *reinterpret_cast<const bf16x8*>(blsb + row * 128 + (kb ^ ((row & 7) << 4)));
            }
#pragma unroll
            for (int mi = 0; mi < 2; ++mi)
#pragma unroll
                for (int ni = 0; ni < 4; ++ni)
                    acc[mi][ni] = __builtin_amdgcn_mfma_f32_16x16x32_bf16(af[mi], bfr[ni], acc[mi][ni], 0, 0, 0);
        }
        __syncthreads();
    }
    int fq = lane >> 4, fr = lane & 15;
#pragma unroll
    for (int mi = 0; mi < 2; ++mi)
#pragma unroll
        for (int ni = 0; ni < 4; ++ni) {
            int col = n0 + wc * 64 + ni * 16 + fr;
#pragma unroll
            for (int j = 0; j < 4; ++j) {
                int row = m0 + wr * 32 + mi * 16 + fq * 4 + j;
                Out[(size_t)row * 512 + col] = acc[mi][ni][j];
            }
        }
}

// ---------------- Tiled neighborhood attention ----------------
// Block = 4x8 query tile (32 q), 4 waves (8 q each), heads sequential.
// Union neighborhood <= 10x14 = 140 pixels staged in LDS (f32, stride 33).
__global__ __launch_bounds__(256) void na_tile_kernel(
    const float* __restrict__ Q, int qld,
    const float* __restrict__ Kx, const float* __restrict__ Vx, int kvld,
    const float* __restrict__ rpb, unsigned short* __restrict__ Out)
{
    __shared__ float Kls[140 * 33];
    __shared__ float Vls[140 * 33];
    __shared__ float Qls[32 * 32];
    __shared__ float a_w[4][64];
    int t = threadIdx.x, lane = t & 63, w = t >> 6;
    int blk = blockIdx.x;
    int b = blk / 98; int rem = blk - b * 98;
    int ti = rem / 7, tj = rem - ti * 7;
    int i0 = ti * 4, j0 = tj * 8;
    int r0 = min(max(i0 - 3, 0), 46), c0 = min(max(j0 - 3, 0), 42);
    int gbase = (b * 56 + r0) * 56 + c0;   // pixel index of union (0,0)
    int ai = lane / 7, aj = lane - ai * 7; // neighbor coords (lane<49)

    for (int h = 0; h < HEADS; ++h) {
        // ---- stage K,V union + Q tile (coalesced 128B rows) ----
        for (int idx = t; idx < 140 * 32; idx += 256) {
            int pr = idx >> 5, c = idx & 31;
            int ur = pr / 14, uc = pr - ur * 14;
            size_t g = (size_t)(gbase + ur * 56 + uc) * kvld + h * 32 + c;
            Kls[pr * 33 + c] = Kx[g];
            Vls[pr * 33 + c] = Vx[g];
        }
        for (int idx = t; idx < 32 * 32; idx += 256) {
            int q = idx >> 5, c = idx & 31;
            int qi = q >> 3, qj = q & 7;
            Qls[idx] = Q[(size_t)((b * 56 + i0 + qi) * 56 + j0 + qj) * qld + h * 32 + c];
        }
        __syncthreads();
        // ---- per-wave: 8 queries ----
        for (int qq = 0; qq < 8; ++qq) {
            int q = w * 8 + qq;
            int qi = q >> 3, qj = q & 7;
            int i = i0 + qi, j = j0 + qj;
            int si = min(max(i - 3, 0), 49), sj = min(max(j - 3, 0), 49);
            int pu_base = (si - r0) * 14 + (sj - c0);
            float s = -1e30f;
            if (lane < 49) {
                const float* kp = &Kls[(pu_base + ai * 14 + aj) * 33];
                const float* qp = &Qls[q * 32];
                float dot = 0.f;
#pragma unroll
                for (int d = 0; d < 32; ++d) dot += qp[d] * kp[d];
                s = dot * 0.17677669529663687f
                  + rpb[h * 169 + (si - i + 6 + ai) * 13 + (sj - j + 6 + aj)];
            }
            float m = s;
#pragma unroll
            for (int o = 32; o > 0; o >>= 1) m = fmaxf(m, __shfl_xor(m, o));
            float e = (lane < 49) ? expf(s - m) : 0.f;
            float sum = e;
#pragma unroll
            for (int o = 32; o > 0; o >>= 1) sum += __shfl_xor(sum, o);
            a_w[w][lane] = e / sum;
            // same wave: LDS dependency handled by hardware waitcnt
            if (lane < 32) {
                float o = 0.f;
#pragma unroll
                for (int n = 0; n < 49; ++n) {
                    int pu = pu_base + (n / 7) * 14 + (n - (n / 7) * 7);
                    o += a_w[w][n] * Vls[pu * 33 + lane];
                }
                Out[(size_t)((b * 56 + i) * 56 + j) * CH + h * 32 + lane] = rne_bf16(o);
            }
        }
        __syncthreads();
    }
}

// ---------------- final LayerNorm over 512, write f32 ----------------
__global__ __launch_bounds__(64) void ln512_out_kernel(const float* __restrict__ in,
    const float* __restrict__ g, const float* __restrict__ b, float* __restrict__ out)
{
    int p = blockIdx.x, lane = threadIdx.x;
    const float4* ip = reinterpret_cast<const float4*>(in + (size_t)p * 512);
    float4 v0 = ip[lane * 2], v1 = ip[lane * 2 + 1];
    float vals[8] = { v0.x, v0.y, v0.z, v0.w, v1.x, v1.y, v1.z, v1.w };
    float s = 0.f, sq = 0.f;
#pragma unroll
    for (int q = 0; q < 8; ++q) { s += vals[q]; sq += vals[q] * vals[q]; }
#pragma unroll
    for (int o = 32; o > 0; o >>= 1) { s += __shfl_xor(s, o); sq += __shfl_xor(sq, o); }
    float mean = s * (1.0f / 512.0f);
    float inv = rsqrtf(sq * (1.0f / 512.0f) - mean * mean + 1e-5f);
#pragma unroll
    for (int q = 0; q < 8; ++q) {
        int c = lane * 8 + q;
        out[(size_t)p * 512 + c] = (vals[q] - mean) * inv * g[c] + b[c];
    }
}

extern "C" void kernel_launch(void* const* d_in, const int* in_sizes, int n_in,
                              void* d_out, int out_size, void* d_ws, size_t ws_size,
                              hipStream_t stream)
{
    const float* X      = (const float*)d_in[0];
    const float* XM     = (const float*)d_in[1];
    const float* sa_n1g = (const float*)d_in[2];
    const float* sa_n1b = (const float*)d_in[3];
    const float* sa_qkvw= (const float*)d_in[4];
    const float* sa_qkvb= (const float*)d_in[5];
    const float* sa_rpb = (const float*)d_in[6];
    const float* sa_pw  = (const float*)d_in[7];
    const float* sa_pb  = (const float*)d_in[8];
    const float* sa_n2g = (const float*)d_in[9];
    const float* sa_n2b = (const float*)d_in[10];
    const float* sa_f1w = (const float*)d_in[11];
    const float* sa_f1b = (const float*)d_in[12];
    const float* sa_f2w = (const float*)d_in[13];
    const float* sa_f2b = (const float*)d_in[14];
    const float* cr_n1g = (const float*)d_in[15];
    const float* cr_n1b = (const float*)d_in[16];
    const float* cr_qw  = (const float*)d_in[17];
    const float* cr_qb  = (const float*)d_in[18];
    const float* cr_kvw = (const float*)d_in[19];
    const float* cr_kvb = (const float*)d_in[20];
    const float* cr_rpb = (const float*)d_in[21];
    const float* cr_pw  = (const float*)d_in[22];
    const float* cr_pb  = (const float*)d_in[23];
    const float* cr_n2g = (const float*)d_in[24];
    const float* cr_n2b = (const float*)d_in[25];
    const float* cr_f1w = (const float*)d_in[26];
    const float* cr_f1b = (const float*)d_in[27];
    const float* cr_f2w = (const float*)d_in[28];
    const float* cr_f2b = (const float*)d_in[29];
    const float* dconvw = (const float*)d_in[30];
    const float* ds_ng  = (const float*)d_in[31];
    const float* ds_nb  = (const float*)d_in[32];

    const size_t NC = (size_t)NPIX * CH;       // 1,605,632
    float* ws   = (float*)d_ws;
    float* xb   = ws;
    float* xcb  = xb + NC;
    float* bufQ = xcb + NC;
    float* big  = bufQ + NC;                   // [NPIX,512] f32
    unsigned short* hnb   = (unsigned short*)(big + (size_t)NPIX * 512);
    unsigned short* attnb = hnb + NC;
    unsigned short* xcbbf = attnb + NC;
    unsigned short* wa    = xcbbf + NC;        // bf16 weight arena (~2.0M elems)
    unsigned short* bigb  = (unsigned short*)big;  // alias: fc1 bf16 out (safe: qkv/kv dead by then)

    // ---- weight arena layout + transpose descriptors ----
    TPack tp;
    int tile = 0, idx = 0;
    unsigned short* p = wa;
    unsigned short* qkvt[2]; unsigned short* pwt[2]; unsigned short* f1t[2]; unsigned short* f2t[2];
    unsigned short* qt[2];   unsigned short* kvt[2]; unsigned short* cpt[2]; unsigned short* cf1t[2];
    unsigned short* cf2t[2]; unsigned short* convt;
    auto add = [&](const float* s, unsigned short*& dst, int K, int N) {
        dst = p;
        tp.d[idx].src = s; tp.d[idx].dst = p; tp.d[idx].K = K; tp.d[idx].N = N; tp.d[idx].tile0 = tile;
        tile += (K / 32) * (N / 32); p += (size_t)K * N; ++idx;
    };
    for (int l = 0; l < 2; ++l) add(sa_qkvw + (size_t)l * 128 * 384, qkvt[l], 128, 384);
    for (int l = 0; l < 2; ++l) add(sa_pw   + (size_t)l * 128 * 128, pwt[l],  128, 128);
    for (int l = 0; l < 2; ++l) add(sa_f1w  + (size_t)l * 128 * 512, f1t[l],  128, 512);
    for (int l = 0; l < 2; ++l) add(sa_f2w  + (size_t)l * 512 * 128, f2t[l],  512, 128);
    for (int l = 0; l < 2; ++l) add(cr_qw   + (size_t)l * 128 * 128, qt[l],   128, 128);
    for (int l = 0; l < 2; ++l) add(cr_kvw  + (size_t)l * 128 * 256, kvt[l],  128, 256);
    for (int l = 0; l < 2; ++l) add(cr_pw   + (size_t)l * 128 * 128, cpt[l],  128, 128);
    for (int l = 0; l < 2; ++l) add(cr_f1w  + (size_t)l * 128 * 512, cf1t[l], 128, 512);
    for (int l = 0; l < 2; ++l) add(cr_f2w  + (size_t)l * 512 * 128, cf2t[l], 512, 128);
    add(dconvw, convt, 2304, 512);

    wtrans_kernel<<<tile, 256, 0, stream>>>(tp);

    const int n4 = NPIX * CH / 4;
    dup_kernel<<<(n4 + 255) / 256, 256, 0, stream>>>(X, xb, xcb, n4);

    // ---- self-attention layers ----
    for (int l = 0; l < 2; ++l) {
        ln128_kernel<<<NPIX, 64, 0, stream>>>(xb, sa_n1g + l * CH, sa_n1b + l * CH, hnb);
        mfma_gemm_kernel<128, 0><<<dim3(NPIX / 128, 3), 256, 0, stream>>>(
            hnb, qkvt[l], sa_qkvb + l * 384, nullptr, big, nullptr, NPIX, 384, 128);
        na_tile_kernel<<<392, 256, 0, stream>>>(big, 384, big + 128, big + 256, 384,
                                                sa_rpb + l * HEADS * 169, attnb);
        mfma_gemm_kernel<64, 2><<<dim3(NPIX / 128, 2), 256, 0, stream>>>(
            attnb, pwt[l], sa_pb + l * CH, xb, xb, nullptr, NPIX, 128, 128);
        ln128_kernel<<<NPIX, 64, 0, stream>>>(xb, sa_n2g + l * CH, sa_n2b + l * CH, hnb);
        mfma_gemm_kernel<128, 1><<<dim3(NPIX / 128, 4), 256, 0, stream>>>(
            hnb, f1t[l], sa_f1b + l * HID, nullptr, nullptr, bigb, NPIX, 512, 128);
        mfma_gemm_kernel<64, 2><<<dim3(NPIX / 128, 2), 256, 0, stream>>>(
            bigb, f2t[l], sa_f2b + l * CH, xb, xb, nullptr, NPIX, 128, 512);
    }

    // ---- cross layers ----
    for (int l = 0; l < 2; ++l) {
        ln128_kernel<<<NPIX, 64, 0, stream>>>(XM, cr_n1g + l * CH, cr_n1b + l * CH, hnb);
        cvtb_kernel<<<(n4 + 255) / 256, 256, 0, stream>>>(xcb, xcbbf, n4);
        mfma_gemm_kernel<64, 0><<<dim3(NPIX / 128, 2), 256, 0, stream>>>(
            xcbbf, qt[l], cr_qb + l * CH, nullptr, bufQ, nullptr, NPIX, 128, 128);
        mfma_gemm_kernel<128, 0><<<dim3(NPIX / 128, 2), 256, 0, stream>>>(
            hnb, kvt[l], cr_kvb + l * 256, nullptr, big, nullptr, NPIX, 256, 128);
        na_tile_kernel<<<392, 256, 0, stream>>>(bufQ, 128, big, big + 128, 256,
                                                cr_rpb + l * HEADS * 169, attnb);
        mfma_gemm_kernel<64, 2><<<dim3(NPIX / 128, 2), 256, 0, stream>>>(
            attnb, cpt[l], cr_pb + l * CH, XM, xcb, nullptr, NPIX, 128, 128);
        ln128_kernel<<<NPIX, 64, 0, stream>>>(xcb, cr_n2g + l * CH, cr_n2b + l * CH, hnb);
        mfma_gemm_kernel<128, 1><<<dim3(NPIX / 128, 4), 256, 0, stream>>>(
            hnb, cf1t[l], cr_f1b + l * HID, nullptr, nullptr, bigb, NPIX, 512, 128);
        mfma_gemm_kernel<64, 2><<<dim3(NPIX / 128, 2), 256, 0, stream>>>(
            bigb, cf2t[l], cr_f2b + l * CH, xcb, xcb, nullptr, NPIX, 128, 512);
    }

    // ---- downsample conv (MFMA implicit GEMM) + final LN ----
    cvtb_kernel<<<(n4 + 255) / 256, 256, 0, stream>>>(xb, hnb, n4);
    cvtb_kernel<<<(n4 + 255) / 256, 256, 0, stream>>>(xcb, attnb, n4);
    conv_mfma_kernel<<<dim3(3136 / 64, 4), 256, 0, stream>>>(hnb, attnb, convt, big);
    ln512_out_kernel<<<3136, 64, 0, stream>>>(big, ds_ng, ds_nb, (float*)d_out);
}

// Round 6
// 444.255 us; speedup vs baseline: 3.7413x; 1.1771x over previous
//
#include <hip/hip_runtime.h>
#include <math.h>

#define NPIX 12544   // B*H*W = 4*56*56
#define CH   128
#define HEADS 4
#define HD   32
#define KS   7
#define HID  512
#define HH   56
#define WW   56

typedef __attribute__((ext_vector_type(8))) short bf16x8;
typedef __attribute__((ext_vector_type(4))) float f32x4;

__device__ inline float gelu_f(float x) { return 0.5f * x * (1.0f + erff(x * 0.70710678118654752f)); }

__device__ inline unsigned short rne_bf16(float x) {
    unsigned u = __float_as_uint(x);
    return (unsigned short)((u + 0x7fffu + ((u >> 16) & 1u)) >> 16);
}
__device__ inline float bf2f(unsigned short u) {
    return __uint_as_float(((unsigned)u) << 16);
}

// ---------------- copy f32 (duplicated into two state buffers) ----------------
__global__ __launch_bounds__(256) void dup_kernel(const float* __restrict__ in,
    float* __restrict__ o1, float* __restrict__ o2, int n4)
{
    int i = blockIdx.x * 256 + threadIdx.x;
    if (i < n4) {
        float4 v = reinterpret_cast<const float4*>(in)[i];
        reinterpret_cast<float4*>(o1)[i] = v;
        reinterpret_cast<float4*>(o2)[i] = v;
    }
}

// ---------------- f32 -> bf16 elementwise ----------------
__global__ __launch_bounds__(256) void cvtb_kernel(const float* __restrict__ in,
    unsigned short* __restrict__ out, int n4)
{
    int i = blockIdx.x * 256 + threadIdx.x;
    if (i < n4) {
        float4 v = reinterpret_cast<const float4*>(in)[i];
        ushort4 o;
        o.x = rne_bf16(v.x); o.y = rne_bf16(v.y); o.z = rne_bf16(v.z); o.w = rne_bf16(v.w);
        reinterpret_cast<ushort4*>(out)[i] = o;
    }
}

// ---------------- weight transpose + convert: f32 [K][N] -> bf16 [N][K] ----------------
struct TDesc { const float* src; unsigned short* dst; int K; int N; int tile0; };
struct TPack { TDesc d[19]; };

__global__ __launch_bounds__(256) void wtrans_kernel(TPack p)
{
    __shared__ float tl[32][33];
    int tile = blockIdx.x;
    int i = 0;
#pragma unroll 1
    while (i < 18 && tile >= p.d[i + 1].tile0) ++i;
    TDesc d = p.d[i];
    int local = tile - d.tile0;
    int ktiles = d.K >> 5;
    int lk = local % ktiles, ln_ = local / ktiles;
    int k0 = lk * 32, n0 = ln_ * 32;
    int tx = threadIdx.x & 31, ty = threadIdx.x >> 5;
#pragma unroll
    for (int r = 0; r < 4; ++r) {
        int row = ty * 4 + r;
        tl[row][tx] = d.src[(size_t)(k0 + row) * d.N + n0 + tx];
    }
    __syncthreads();
#pragma unroll
    for (int r = 0; r < 4; ++r) {
        int row = ty * 4 + r;
        d.dst[(size_t)(n0 + row) * d.K + k0 + tx] = rne_bf16(tl[tx][row]);
    }
}

// ---------------- LayerNorm over C=128, one wave per row, bf16 out ----------------
__global__ __launch_bounds__(64) void ln128_kernel(const float* __restrict__ in,
    const float* __restrict__ g, const float* __restrict__ b, unsigned short* __restrict__ out)
{
    int p = blockIdx.x, lane = threadIdx.x;
    float2 v = reinterpret_cast<const float2*>(in + (size_t)p * CH)[lane];
    float s = v.x + v.y, sq = v.x * v.x + v.y * v.y;
#pragma unroll
    for (int o = 32; o > 0; o >>= 1) { s += __shfl_xor(s, o); sq += __shfl_xor(sq, o); }
    float mean = s * (1.0f / CH);
    float inv = rsqrtf(sq * (1.0f / CH) - mean * mean + 1e-5f);
    float2 gg = reinterpret_cast<const float2*>(g)[lane];
    float2 bb = reinterpret_cast<const float2*>(b)[lane];
    ushort2 o;
    o.x = rne_bf16((v.x - mean) * inv * gg.x + bb.x);
    o.y = rne_bf16((v.y - mean) * inv * gg.y + bb.y);
    reinterpret_cast<ushort2*>(out + (size_t)p * CH)[lane] = o;
}

// ---------------- MFMA GEMM: A bf16 [M][K], Bt bf16 [N][K] -> C [M][N] ----------------
// MODE 0: f32 = acc+bias ; MODE 1: bf16 = gelu(acc+bias) ; MODE 2: f32 = acc+bias+res
template<int BN, int MODE>
__global__ __launch_bounds__(256) void mfma_gemm_kernel(
    const unsigned short* __restrict__ A, const unsigned short* __restrict__ Bt,
    const float* __restrict__ bias, const float* __restrict__ res,
    float* __restrict__ Cf, unsigned short* __restrict__ Cb,
    int M, int N, int K)
{
    constexpr int MF = 4, NF = BN / 32;
    __shared__ unsigned short Als[128 * 64];
    __shared__ unsigned short Bls[BN * 64];
    char* alsb = reinterpret_cast<char*>(Als);
    char* blsb = reinterpret_cast<char*>(Bls);
    int t = threadIdx.x;
    int m0 = blockIdx.x * 128, n0 = blockIdx.y * BN;
    int lane = t & 63, w = t >> 6;
    int wr = w >> 1, wc = w & 1;
    f32x4 acc[MF][NF] = {};
    for (int k0 = 0; k0 < K; k0 += 64) {
#pragma unroll
        for (int i = 0; i < 4; ++i) {
            int s = t + i * 256, row = s >> 3, ch = (s & 7) * 8;
            bf16x8 v = *reinterpret_cast<const bf16x8*>(A + (size_t)(m0 + row) * K + k0 + ch);
            *reinterpret_cast<bf16x8*>(alsb + row * 128 + ((ch * 2) ^ ((row & 7) << 4))) = v;
        }
#pragma unroll
        for (int i = 0; i < NF; ++i) {
            int s = t + i * 256, row = s >> 3, ch = (s & 7) * 8;
            bf16x8 v = *reinterpret_cast<const bf16x8*>(Bt + (size_t)(n0 + row) * K + k0 + ch);
            *reinterpret_cast<bf16x8*>(blsb + row * 128 + ((ch * 2) ^ ((row & 7) << 4))) = v;
        }
        __syncthreads();
#pragma unroll
        for (int kk = 0; kk < 2; ++kk) {
            int kb = kk * 64 + (lane >> 4) * 16;
            bf16x8 af[MF], bfr[NF];
#pragma unroll
            for (int mi = 0; mi < MF; ++mi) {
                int row = wr * 64 + mi * 16 + (lane & 15);
                af[mi] = *reinterpret_cast<const bf16x8*>(alsb + row * 128 + (kb ^ ((row & 7) << 4)));
            }
#pragma unroll
            for (int ni = 0; ni < NF; ++ni) {
                int row = wc * (BN / 2) + ni * 16 + (lane & 15);
                bfr[ni] = *reinterpret_cast<const bf16x8*>(blsb + row * 128 + (kb ^ ((row & 7) << 4)));
            }
#pragma unroll
            for (int mi = 0; mi < MF; ++mi)
#pragma unroll
                for (int ni = 0; ni < NF; ++ni)
                    acc[mi][ni] = __builtin_amdgcn_mfma_f32_16x16x32_bf16(af[mi], bfr[ni], acc[mi][ni], 0, 0, 0);
        }
        __syncthreads();
    }
    int fq = lane >> 4, fr = lane & 15;
#pragma unroll
    for (int mi = 0; mi < MF; ++mi) {
#pragma unroll
        for (int ni = 0; ni < NF; ++ni) {
            int col = n0 + wc * (BN / 2) + ni * 16 + fr;
            float bv = bias[col];
#pragma unroll
            for (int j = 0; j < 4; ++j) {
                int row = m0 + wr * 64 + mi * 16 + fq * 4 + j;
                float v = acc[mi][ni][j] + bv;
                if constexpr (MODE == 1) {
                    Cb[(size_t)row * N + col] = rne_bf16(gelu_f(v));
                } else if constexpr (MODE == 2) {
                    Cf[(size_t)row * N + col] = v + res[(size_t)row * N + col];
                } else {
                    Cf[(size_t)row * N + col] = v;
                }
            }
        }
    }
}

// ---------------- conv as MFMA implicit GEMM: M=3136 (BM=64), N=512 (BN=128), K=2304 ----------------
__global__ __launch_bounds__(256) void conv_mfma_kernel(
    const unsigned short* __restrict__ Xb, const unsigned short* __restrict__ Xc,
    const unsigned short* __restrict__ Wt, float* __restrict__ Out)
{
    __shared__ unsigned short Als[64 * 64];
    __shared__ unsigned short Bls[128 * 64];
    char* alsb = reinterpret_cast<char*>(Als);
    char* blsb = reinterpret_cast<char*>(Bls);
    int t = threadIdx.x;
    int m0 = blockIdx.x * 64, n0 = blockIdx.y * 128;
    int lane = t & 63, w = t >> 6, wr = w >> 1, wc = w & 1;

    int rowi[2], chv[2], pb[2], ib[2], jb[2];
#pragma unroll
    for (int i = 0; i < 2; ++i) {
        int s = t + i * 256;
        rowi[i] = s >> 3; chv[i] = (s & 7) * 8;
        int pm = m0 + rowi[i];
        int b = pm / 784; int rem = pm - b * 784;
        int oi = rem / 28, oj = rem - oi * 28;
        pb[i] = b * 56; ib[i] = 2 * oi - 1; jb[i] = 2 * oj - 1;
    }
    f32x4 acc[2][4] = {};
    for (int k0 = 0; k0 < 2304; k0 += 64) {
#pragma unroll
        for (int i = 0; i < 2; ++i) {
            int row = rowi[i];
            int k = k0 + chv[i];
            int tap = k >> 8, c = k & 255;
            int ky = (tap * 11) >> 5, kx = tap - ky * 3;
            int ii = ib[i] + ky, jj = jb[i] + kx;
            bf16x8 v = {};
            if ((unsigned)ii < 56u && (unsigned)jj < 56u) {
                const unsigned short* src = (c < 128) ? Xb : Xc;
                v = *reinterpret_cast<const bf16x8*>(src + (size_t)((pb[i] + ii) * 56 + jj) * 128 + (c & 127));
            }
            *reinterpret_cast<bf16x8*>(alsb + row * 128 + ((chv[i] * 2) ^ ((row & 7) << 4))) = v;
        }
#pragma unroll
        for (int i = 0; i < 4; ++i) {
            int s = t + i * 256, row = s >> 3, ch = (s & 7) * 8;
            bf16x8 v = *reinterpret_cast<const bf16x8*>(Wt + (size_t)(n0 + row) * 2304 + k0 + ch);
            *reinterpret_cast<bf16x8*>(blsb + row * 128 + ((ch * 2) ^ ((row & 7) << 4))) = v;
        }
        __syncthreads();
#pragma unroll
        for (int kk = 0; kk < 2; ++kk) {
            int kb = kk * 64 + (lane >> 4) * 16;
            bf16x8 af[2], bfr[4];
#pragma unroll
            for (int mi = 0; mi < 2; ++mi) {
                int row = wr * 32 + mi * 16 + (lane & 15);
                af[mi] = *reinterpret_cast<const bf16x8*>(alsb + row * 128 + (kb ^ ((row & 7) << 4)));
            }
#pragma unroll
            for (int ni = 0; ni < 4; ++ni) {
                int row = wc * 64 + ni * 16 + (lane & 15);
                bfr[ni] = *reinterpret_cast<const bf16x8*>(blsb + row * 128 + (kb ^ ((row & 7) << 4)));
            }
#pragma unroll
            for (int mi = 0; mi < 2; ++mi)
#pragma unroll
                for (int ni = 0; ni < 4; ++ni)
                    acc[mi][ni] = __builtin_amdgcn_mfma_f32_16x16x32_bf16(af[mi], bfr[ni], acc[mi][ni], 0, 0, 0);
        }
        __syncthreads();
    }
    int fq = lane >> 4, fr = lane & 15;
#pragma unroll
    for (int mi = 0; mi < 2; ++mi)
#pragma unroll
        for (int ni = 0; ni < 4; ++ni) {
            int col = n0 + wc * 64 + ni * 16 + fr;
#pragma unroll
            for (int j = 0; j < 4; ++j) {
                int row = m0 + wr * 32 + mi * 16 + fq * 4 + j;
                Out[(size_t)row * 512 + col] = acc[mi][ni][j];
            }
        }
}

// ---------------- Tiled neighborhood attention, head-parallel ----------------
// Block = (4x8 query tile, one head). Grid (392, 4). 4 waves, 8 queries each.
// K/V union (<=10x14=140 pixels x 32ch) staged as bf16, stride 40 ushort (80B, 16B-aligned).
__global__ __launch_bounds__(256) void na_tile_kernel(
    const float* __restrict__ Q, int qld,
    const float* __restrict__ Kx, const float* __restrict__ Vx, int kvld,
    const float* __restrict__ rpb, unsigned short* __restrict__ Out)
{
    __shared__ unsigned short Kls[140 * 40];
    __shared__ unsigned short Vls[140 * 40];
    __shared__ float Qls[32 * 32];
    __shared__ float a_w[4][64];
    __shared__ float rls[169];
    int t = threadIdx.x, lane = t & 63, w = t >> 6;
    int h = blockIdx.y;
    int blk = blockIdx.x;
    int b = blk / 98; int rem = blk - b * 98;
    int ti = rem / 7, tj = rem - ti * 7;
    int i0 = ti * 4, j0 = tj * 8;
    int r0 = min(max(i0 - 3, 0), 46), c0 = min(max(j0 - 3, 0), 42);
    int gbase = (b * 56 + r0) * 56 + c0;   // pixel index of union (0,0)
    int ai = lane / 7, aj = lane - ai * 7; // neighbor coords (lane<49)

    // ---- stage K,V union (bf16), Q tile (f32), rpb (f32) ----
    for (int idx = t; idx < 140 * 16; idx += 256) {
        int pr = idx >> 4, c2 = (idx & 15) * 2;
        int ur = pr / 14, uc = pr - ur * 14;
        size_t g = (size_t)(gbase + ur * 56 + uc) * kvld + h * 32 + c2;
        float2 kk = *reinterpret_cast<const float2*>(Kx + g);
        float2 vv = *reinterpret_cast<const float2*>(Vx + g);
        ushort2 ko; ko.x = rne_bf16(kk.x); ko.y = rne_bf16(kk.y);
        ushort2 vo; vo.x = rne_bf16(vv.x); vo.y = rne_bf16(vv.y);
        *reinterpret_cast<ushort2*>(&Kls[pr * 40 + c2]) = ko;
        *reinterpret_cast<ushort2*>(&Vls[pr * 40 + c2]) = vo;
    }
    for (int idx = t; idx < 32 * 16; idx += 256) {
        int q = idx >> 4, c2 = (idx & 15) * 2;
        int qi = q >> 3, qj = q & 7;
        *reinterpret_cast<float2*>(&Qls[q * 32 + c2]) =
            *reinterpret_cast<const float2*>(Q + (size_t)((b * 56 + i0 + qi) * 56 + j0 + qj) * qld + h * 32 + c2);
    }
    if (t < 169) rls[t] = rpb[h * 169 + t];
    __syncthreads();

    // ---- per-wave: 8 queries ----
    for (int qq = 0; qq < 8; ++qq) {
        int q = w * 8 + qq;
        int qi = q >> 3, qj = q & 7;
        int i = i0 + qi, j = j0 + qj;
        int si = min(max(i - 3, 0), 49), sj = min(max(j - 3, 0), 49);
        int pu_base = (si - r0) * 14 + (sj - c0);
        float s = -1e30f;
        if (lane < 49) {
            const unsigned short* kp = &Kls[(pu_base + ai * 14 + aj) * 40];
            const float* qp = &Qls[q * 32];
            float dot = 0.f;
#pragma unroll
            for (int d8 = 0; d8 < 4; ++d8) {
                bf16x8 kv8 = *reinterpret_cast<const bf16x8*>(kp + d8 * 8);
#pragma unroll
                for (int e = 0; e < 8; ++e)
                    dot += qp[d8 * 8 + e] * bf2f((unsigned short)kv8[e]);
            }
            s = dot * 0.17677669529663687f
              + rls[(si - i + 6 + ai) * 13 + (sj - j + 6 + aj)];
        }
        float m = s;
#pragma unroll
        for (int o = 32; o > 0; o >>= 1) m = fmaxf(m, __shfl_xor(m, o));
        float e = (lane < 49) ? expf(s - m) : 0.f;
        float sum = e;
#pragma unroll
        for (int o = 32; o > 0; o >>= 1) sum += __shfl_xor(sum, o);
        a_w[w][lane] = e / sum;
        // ---- PV: 64 lanes = 2 neighbor-halves x 32 channels ----
        int c = lane & 31, nh = lane >> 5;
        float o = 0.f;
#pragma unroll 5
        for (int k = 0; k < 25; ++k) {
            int n = nh * 25 + k;
            if (n < 49) {
                int n7 = n / 7;
                int pu = pu_base + n7 * 14 + (n - n7 * 7);
                o += a_w[w][n] * bf2f(Vls[pu * 40 + c]);
            }
        }
        o += __shfl_xor(o, 32);
        if (lane < 32)
            Out[(size_t)((b * 56 + i) * 56 + j) * CH + h * 32 + c] = rne_bf16(o);
    }
}

// ---------------- final LayerNorm over 512, write f32 ----------------
__global__ __launch_bounds__(64) void ln512_out_kernel(const float* __restrict__ in,
    const float* __restrict__ g, const float* __restrict__ b, float* __restrict__ out)
{
    int p = blockIdx.x, lane = threadIdx.x;
    const float4* ip = reinterpret_cast<const float4*>(in + (size_t)p * 512);
    float4 v0 = ip[lane * 2], v1 = ip[lane * 2 + 1];
    float vals[8] = { v0.x, v0.y, v0.z, v0.w, v1.x, v1.y, v1.z, v1.w };
    float s = 0.f, sq = 0.f;
#pragma unroll
    for (int q = 0; q < 8; ++q) { s += vals[q]; sq += vals[q] * vals[q]; }
#pragma unroll
    for (int o = 32; o > 0; o >>= 1) { s += __shfl_xor(s, o); sq += __shfl_xor(sq, o); }
    float mean = s * (1.0f / 512.0f);
    float inv = rsqrtf(sq * (1.0f / 512.0f) - mean * mean + 1e-5f);
#pragma unroll
    for (int q = 0; q < 8; ++q) {
        int c = lane * 8 + q;
        out[(size_t)p * 512 + c] = (vals[q] - mean) * inv * g[c] + b[c];
    }
}

extern "C" void kernel_launch(void* const* d_in, const int* in_sizes, int n_in,
                              void* d_out, int out_size, void* d_ws, size_t ws_size,
                              hipStream_t stream)
{
    const float* X      = (const float*)d_in[0];
    const float* XM     = (const float*)d_in[1];
    const float* sa_n1g = (const float*)d_in[2];
    const float* sa_n1b = (const float*)d_in[3];
    const float* sa_qkvw= (const float*)d_in[4];
    const float* sa_qkvb= (const float*)d_in[5];
    const float* sa_rpb = (const float*)d_in[6];
    const float* sa_pw  = (const float*)d_in[7];
    const float* sa_pb  = (const float*)d_in[8];
    const float* sa_n2g = (const float*)d_in[9];
    const float* sa_n2b = (const float*)d_in[10];
    const float* sa_f1w = (const float*)d_in[11];
    const float* sa_f1b = (const float*)d_in[12];
    const float* sa_f2w = (const float*)d_in[13];
    const float* sa_f2b = (const float*)d_in[14];
    const float* cr_n1g = (const float*)d_in[15];
    const float* cr_n1b = (const float*)d_in[16];
    const float* cr_qw  = (const float*)d_in[17];
    const float* cr_qb  = (const float*)d_in[18];
    const float* cr_kvw = (const float*)d_in[19];
    const float* cr_kvb = (const float*)d_in[20];
    const float* cr_rpb = (const float*)d_in[21];
    const float* cr_pw  = (const float*)d_in[22];
    const float* cr_pb  = (const float*)d_in[23];
    const float* cr_n2g = (const float*)d_in[24];
    const float* cr_n2b = (const float*)d_in[25];
    const float* cr_f1w = (const float*)d_in[26];
    const float* cr_f1b = (const float*)d_in[27];
    const float* cr_f2w = (const float*)d_in[28];
    const float* cr_f2b = (const float*)d_in[29];
    const float* dconvw = (const float*)d_in[30];
    const float* ds_ng  = (const float*)d_in[31];
    const float* ds_nb  = (const float*)d_in[32];

    const size_t NC = (size_t)NPIX * CH;       // 1,605,632
    float* ws   = (float*)d_ws;
    float* xb   = ws;
    float* xcb  = xb + NC;
    float* bufQ = xcb + NC;
    float* big  = bufQ + NC;                   // [NPIX,512] f32
    unsigned short* hnb   = (unsigned short*)(big + (size_t)NPIX * 512);
    unsigned short* attnb = hnb + NC;
    unsigned short* xcbbf = attnb + NC;
    unsigned short* wa    = xcbbf + NC;        // bf16 weight arena (~2.0M elems)
    unsigned short* bigb  = (unsigned short*)big;  // alias: fc1 bf16 out (safe: qkv/kv dead by then)

    // ---- weight arena layout + transpose descriptors ----
    TPack tp;
    int tile = 0, idx = 0;
    unsigned short* p = wa;
    unsigned short* qkvt[2]; unsigned short* pwt[2]; unsigned short* f1t[2]; unsigned short* f2t[2];
    unsigned short* qt[2];   unsigned short* kvt[2]; unsigned short* cpt[2]; unsigned short* cf1t[2];
    unsigned short* cf2t[2]; unsigned short* convt;
    auto add = [&](const float* s, unsigned short*& dst, int K, int N) {
        dst = p;
        tp.d[idx].src = s; tp.d[idx].dst = p; tp.d[idx].K = K; tp.d[idx].N = N; tp.d[idx].tile0 = tile;
        tile += (K / 32) * (N / 32); p += (size_t)K * N; ++idx;
    };
    for (int l = 0; l < 2; ++l) add(sa_qkvw + (size_t)l * 128 * 384, qkvt[l], 128, 384);
    for (int l = 0; l < 2; ++l) add(sa_pw   + (size_t)l * 128 * 128, pwt[l],  128, 128);
    for (int l = 0; l < 2; ++l) add(sa_f1w  + (size_t)l * 128 * 512, f1t[l],  128, 512);
    for (int l = 0; l < 2; ++l) add(sa_f2w  + (size_t)l * 512 * 128, f2t[l],  512, 128);
    for (int l = 0; l < 2; ++l) add(cr_qw   + (size_t)l * 128 * 128, qt[l],   128, 128);
    for (int l = 0; l < 2; ++l) add(cr_kvw  + (size_t)l * 128 * 256, kvt[l],  128, 256);
    for (int l = 0; l < 2; ++l) add(cr_pw   + (size_t)l * 128 * 128, cpt[l],  128, 128);
    for (int l = 0; l < 2; ++l) add(cr_f1w  + (size_t)l * 128 * 512, cf1t[l], 128, 512);
    for (int l = 0; l < 2; ++l) add(cr_f2w  + (size_t)l * 512 * 128, cf2t[l], 512, 128);
    add(dconvw, convt, 2304, 512);

    wtrans_kernel<<<tile, 256, 0, stream>>>(tp);

    const int n4 = NPIX * CH / 4;
    dup_kernel<<<(n4 + 255) / 256, 256, 0, stream>>>(X, xb, xcb, n4);

    // ---- self-attention layers ----
    for (int l = 0; l < 2; ++l) {
        ln128_kernel<<<NPIX, 64, 0, stream>>>(xb, sa_n1g + l * CH, sa_n1b + l * CH, hnb);
        mfma_gemm_kernel<128, 0><<<dim3(NPIX / 128, 3), 256, 0, stream>>>(
            hnb, qkvt[l], sa_qkvb + l * 384, nullptr, big, nullptr, NPIX, 384, 128);
        na_tile_kernel<<<dim3(392, 4), 256, 0, stream>>>(big, 384, big + 128, big + 256, 384,
                                                         sa_rpb + l * HEADS * 169, attnb);
        mfma_gemm_kernel<64, 2><<<dim3(NPIX / 128, 2), 256, 0, stream>>>(
            attnb, pwt[l], sa_pb + l * CH, xb, xb, nullptr, NPIX, 128, 128);
        ln128_kernel<<<NPIX, 64, 0, stream>>>(xb, sa_n2g + l * CH, sa_n2b + l * CH, hnb);
        mfma_gemm_kernel<128, 1><<<dim3(NPIX / 128, 4), 256, 0, stream>>>(
            hnb, f1t[l], sa_f1b + l * HID, nullptr, nullptr, bigb, NPIX, 512, 128);
        mfma_gemm_kernel<64, 2><<<dim3(NPIX / 128, 2), 256, 0, stream>>>(
            bigb, f2t[l], sa_f2b + l * CH, xb, xb, nullptr, NPIX, 128, 512);
    }

    // ---- cross layers ----
    for (int l = 0; l < 2; ++l) {
        ln128_kernel<<<NPIX, 64, 0, stream>>>(XM, cr_n1g + l * CH, cr_n1b + l * CH, hnb);
        cvtb_kernel<<<(n4 + 255) / 256, 256, 0, stream>>>(xcb, xcbbf, n4);
        mfma_gemm_kernel<64, 0><<<dim3(NPIX / 128, 2), 256, 0, stream>>>(
            xcbbf, qt[l], cr_qb + l * CH, nullptr, bufQ, nullptr, NPIX, 128, 128);
        mfma_gemm_kernel<128, 0><<<dim3(NPIX / 128, 2), 256, 0, stream>>>(
            hnb, kvt[l], cr_kvb + l * 256, nullptr, big, nullptr, NPIX, 256, 128);
        na_tile_kernel<<<dim3(392, 4), 256, 0, stream>>>(bufQ, 128, big, big + 128, 256,
                                                         cr_rpb + l * HEADS * 169, attnb);
        mfma_gemm_kernel<64, 2><<<dim3(NPIX / 128, 2), 256, 0, stream>>>(
            attnb, cpt[l], cr_pb + l * CH, XM, xcb, nullptr, NPIX, 128, 128);
        ln128_kernel<<<NPIX, 64, 0, stream>>>(xcb, cr_n2g + l * CH, cr_n2b + l * CH, hnb);
        mfma_gemm_kernel<128, 1><<<dim3(NPIX / 128, 4), 256, 0, stream>>>(
            hnb, cf1t[l], cr_f1b + l * HID, nullptr, nullptr, bigb, NPIX, 512, 128);
        mfma_gemm_kernel<64, 2><<<dim3(NPIX / 128, 2), 256, 0, stream>>>(
            bigb, cf2t[l], cr_f2b + l * CH, xcb, xcb, nullptr, NPIX, 128, 512);
    }

    // ---- downsample conv (MFMA implicit GEMM) + final LN ----
    cvtb_kernel<<<(n4 + 255) / 256, 256, 0, stream>>>(xb, hnb, n4);
    cvtb_kernel<<<(n4 + 255) / 256, 256, 0, stream>>>(xcb, attnb, n4);
    conv_mfma_kernel<<<dim3(3136 / 64, 4), 256, 0, stream>>>(hnb, attnb, convt, big);
    ln512_out_kernel<<<3136, 64, 0, stream>>>(big, ds_ng, ds_nb, (float*)d_out);
}

// Round 7
// 365.453 us; speedup vs baseline: 4.5480x; 1.2156x over previous
//
#include <hip/hip_runtime.h>
#include <math.h>

#define NPIX 12544   // B*H*W = 4*56*56
#define CH   128
#define HEADS 4
#define HD   32
#define KS   7
#define HID  512
#define HH   56
#define WW   56

typedef __attribute__((ext_vector_type(8))) short bf16x8;
typedef __attribute__((ext_vector_type(4))) float f32x4;
typedef unsigned short u16;

__device__ inline float gelu_f(float x) { return 0.5f * x * (1.0f + erff(x * 0.70710678118654752f)); }

__device__ inline u16 rne_bf16(float x) {
    unsigned u = __float_as_uint(x);
    return (u16)((u + 0x7fffu + ((u >> 16) & 1u)) >> 16);
}
__device__ inline float bf2f(u16 u) {
    return __uint_as_float(((unsigned)u) << 16);
}

// ---------------- copy f32 (duplicated into two state buffers) ----------------
__global__ __launch_bounds__(256) void dup_kernel(const float* __restrict__ in,
    float* __restrict__ o1, float* __restrict__ o2, int n4)
{
    int i = blockIdx.x * 256 + threadIdx.x;
    if (i < n4) {
        float4 v = reinterpret_cast<const float4*>(in)[i];
        reinterpret_cast<float4*>(o1)[i] = v;
        reinterpret_cast<float4*>(o2)[i] = v;
    }
}

// ---------------- f32 -> bf16 elementwise ----------------
__global__ __launch_bounds__(256) void cvtb_kernel(const float* __restrict__ in,
    u16* __restrict__ out, int n4)
{
    int i = blockIdx.x * 256 + threadIdx.x;
    if (i < n4) {
        float4 v = reinterpret_cast<const float4*>(in)[i];
        ushort4 o;
        o.x = rne_bf16(v.x); o.y = rne_bf16(v.y); o.z = rne_bf16(v.z); o.w = rne_bf16(v.w);
        reinterpret_cast<ushort4*>(out)[i] = o;
    }
}

// ---------------- weight transpose + convert: f32 [K][N] -> bf16 [N][K] ----------------
struct TDesc { const float* src; u16* dst; int K; int N; int tile0; };
struct TPack { TDesc d[19]; };

__global__ __launch_bounds__(256) void wtrans_kernel(TPack p)
{
    __shared__ float tl[32][33];
    int tile = blockIdx.x;
    int i = 0;
#pragma unroll 1
    while (i < 18 && tile >= p.d[i + 1].tile0) ++i;
    TDesc d = p.d[i];
    int local = tile - d.tile0;
    int ktiles = d.K >> 5;
    int lk = local % ktiles, ln_ = local / ktiles;
    int k0 = lk * 32, n0 = ln_ * 32;
    int tx = threadIdx.x & 31, ty = threadIdx.x >> 5;
#pragma unroll
    for (int r = 0; r < 4; ++r) {
        int row = ty * 4 + r;
        tl[row][tx] = d.src[(size_t)(k0 + row) * d.N + n0 + tx];
    }
    __syncthreads();
#pragma unroll
    for (int r = 0; r < 4; ++r) {
        int row = ty * 4 + r;
        d.dst[(size_t)(n0 + row) * d.K + k0 + tx] = rne_bf16(tl[tx][row]);
    }
}

// ---------------- LayerNorm over C=128, one wave per row, bf16 out ----------------
__global__ __launch_bounds__(64) void ln128_kernel(const float* __restrict__ in,
    const float* __restrict__ g, const float* __restrict__ b, u16* __restrict__ out)
{
    int p = blockIdx.x, lane = threadIdx.x;
    float2 v = reinterpret_cast<const float2*>(in + (size_t)p * CH)[lane];
    float s = v.x + v.y, sq = v.x * v.x + v.y * v.y;
#pragma unroll
    for (int o = 32; o > 0; o >>= 1) { s += __shfl_xor(s, o); sq += __shfl_xor(sq, o); }
    float mean = s * (1.0f / CH);
    float inv = rsqrtf(sq * (1.0f / CH) - mean * mean + 1e-5f);
    float2 gg = reinterpret_cast<const float2*>(g)[lane];
    float2 bb = reinterpret_cast<const float2*>(b)[lane];
    ushort2 o;
    o.x = rne_bf16((v.x - mean) * inv * gg.x + bb.x);
    o.y = rne_bf16((v.y - mean) * inv * gg.y + bb.y);
    reinterpret_cast<ushort2*>(out + (size_t)p * CH)[lane] = o;
}

// ---------------- MFMA GEMM: A bf16 [M][K], Bt bf16 [N][K] -> C [M][N] ----------------
// MODE 0: f32 = acc+bias ; MODE 1: bf16 = gelu(acc+bias) ; MODE 2: f32 = acc+bias+res ; MODE 3: bf16 = acc+bias
template<int BN, int MODE>
__global__ __launch_bounds__(256) void mfma_gemm_kernel(
    const u16* __restrict__ A, const u16* __restrict__ Bt,
    const float* __restrict__ bias, const float* __restrict__ res,
    float* __restrict__ Cf, u16* __restrict__ Cb,
    int M, int N, int K)
{
    constexpr int MF = 4, NF = BN / 32;
    __shared__ u16 Als[128 * 64];
    __shared__ u16 Bls[BN * 64];
    char* alsb = reinterpret_cast<char*>(Als);
    char* blsb = reinterpret_cast<char*>(Bls);
    int t = threadIdx.x;
    int m0 = blockIdx.x * 128, n0 = blockIdx.y * BN;
    int lane = t & 63, w = t >> 6;
    int wr = w >> 1, wc = w & 1;
    f32x4 acc[MF][NF] = {};
    for (int k0 = 0; k0 < K; k0 += 64) {
#pragma unroll
        for (int i = 0; i < 4; ++i) {
            int s = t + i * 256, row = s >> 3, ch = (s & 7) * 8;
            bf16x8 v = *reinterpret_cast<const bf16x8*>(A + (size_t)(m0 + row) * K + k0 + ch);
            *reinterpret_cast<bf16x8*>(alsb + row * 128 + ((ch * 2) ^ ((row & 7) << 4))) = v;
        }
#pragma unroll
        for (int i = 0; i < NF; ++i) {
            int s = t + i * 256, row = s >> 3, ch = (s & 7) * 8;
            bf16x8 v = *reinterpret_cast<const bf16x8*>(Bt + (size_t)(n0 + row) * K + k0 + ch);
            *reinterpret_cast<bf16x8*>(blsb + row * 128 + ((ch * 2) ^ ((row & 7) << 4))) = v;
        }
        __syncthreads();
#pragma unroll
        for (int kk = 0; kk < 2; ++kk) {
            int kb = kk * 64 + (lane >> 4) * 16;
            bf16x8 af[MF], bfr[NF];
#pragma unroll
            for (int mi = 0; mi < MF; ++mi) {
                int row = wr * 64 + mi * 16 + (lane & 15);
                af[mi] = *reinterpret_cast<const bf16x8*>(alsb + row * 128 + (kb ^ ((row & 7) << 4)));
            }
#pragma unroll
            for (int ni = 0; ni < NF; ++ni) {
                int row = wc * (BN / 2) + ni * 16 + (lane & 15);
                bfr[ni] = *reinterpret_cast<const bf16x8*>(blsb + row * 128 + (kb ^ ((row & 7) << 4)));
            }
#pragma unroll
            for (int mi = 0; mi < MF; ++mi)
#pragma unroll
                for (int ni = 0; ni < NF; ++ni)
                    acc[mi][ni] = __builtin_amdgcn_mfma_f32_16x16x32_bf16(af[mi], bfr[ni], acc[mi][ni], 0, 0, 0);
        }
        __syncthreads();
    }
    int fq = lane >> 4, fr = lane & 15;
#pragma unroll
    for (int mi = 0; mi < MF; ++mi) {
#pragma unroll
        for (int ni = 0; ni < NF; ++ni) {
            int col = n0 + wc * (BN / 2) + ni * 16 + fr;
            float bv = bias[col];
#pragma unroll
            for (int j = 0; j < 4; ++j) {
                int row = m0 + wr * 64 + mi * 16 + fq * 4 + j;
                float v = acc[mi][ni][j] + bv;
                if constexpr (MODE == 1) {
                    Cb[(size_t)row * N + col] = rne_bf16(gelu_f(v));
                } else if constexpr (MODE == 2) {
                    Cf[(size_t)row * N + col] = v + res[(size_t)row * N + col];
                } else if constexpr (MODE == 3) {
                    Cb[(size_t)row * N + col] = rne_bf16(v);
                } else {
                    Cf[(size_t)row * N + col] = v;
                }
            }
        }
    }
}

// ---------------- conv as MFMA implicit GEMM: M=3136 (BM=64), N=512 (BN=128), K=2304 ----------------
__global__ __launch_bounds__(256) void conv_mfma_kernel(
    const u16* __restrict__ Xb, const u16* __restrict__ Xc,
    const u16* __restrict__ Wt, float* __restrict__ Out)
{
    __shared__ u16 Als[64 * 64];
    __shared__ u16 Bls[128 * 64];
    char* alsb = reinterpret_cast<char*>(Als);
    char* blsb = reinterpret_cast<char*>(Bls);
    int t = threadIdx.x;
    int m0 = blockIdx.x * 64, n0 = blockIdx.y * 128;
    int lane = t & 63, w = t >> 6, wr = w >> 1, wc = w & 1;

    int rowi[2], chv[2], pb[2], ib[2], jb[2];
#pragma unroll
    for (int i = 0; i < 2; ++i) {
        int s = t + i * 256;
        rowi[i] = s >> 3; chv[i] = (s & 7) * 8;
        int pm = m0 + rowi[i];
        int b = pm / 784; int rem = pm - b * 784;
        int oi = rem / 28, oj = rem - oi * 28;
        pb[i] = b * 56; ib[i] = 2 * oi - 1; jb[i] = 2 * oj - 1;
    }
    f32x4 acc[2][4] = {};
    for (int k0 = 0; k0 < 2304; k0 += 64) {
#pragma unroll
        for (int i = 0; i < 2; ++i) {
            int row = rowi[i];
            int k = k0 + chv[i];
            int tap = k >> 8, c = k & 255;
            int ky = (tap * 11) >> 5, kx = tap - ky * 3;
            int ii = ib[i] + ky, jj = jb[i] + kx;
            bf16x8 v = {};
            if ((unsigned)ii < 56u && (unsigned)jj < 56u) {
                const u16* src = (c < 128) ? Xb : Xc;
                v = *reinterpret_cast<const bf16x8*>(src + (size_t)((pb[i] + ii) * 56 + jj) * 128 + (c & 127));
            }
            *reinterpret_cast<bf16x8*>(alsb + row * 128 + ((chv[i] * 2) ^ ((row & 7) << 4))) = v;
        }
#pragma unroll
        for (int i = 0; i < 4; ++i) {
            int s = t + i * 256, row = s >> 3, ch = (s & 7) * 8;
            bf16x8 v = *reinterpret_cast<const bf16x8*>(Wt + (size_t)(n0 + row) * 2304 + k0 + ch);
            *reinterpret_cast<bf16x8*>(blsb + row * 128 + ((ch * 2) ^ ((row & 7) << 4))) = v;
        }
        __syncthreads();
#pragma unroll
        for (int kk = 0; kk < 2; ++kk) {
            int kb = kk * 64 + (lane >> 4) * 16;
            bf16x8 af[2], bfr[4];
#pragma unroll
            for (int mi = 0; mi < 2; ++mi) {
                int row = wr * 32 + mi * 16 + (lane & 15);
                af[mi] = *reinterpret_cast<const bf16x8*>(alsb + row * 128 + (kb ^ ((row & 7) << 4)));
            }
#pragma unroll
            for (int ni = 0; ni < 4; ++ni) {
                int row = wc * 64 + ni * 16 + (lane & 15);
                bfr[ni] = *reinterpret_cast<const bf16x8*>(blsb + row * 128 + (kb ^ ((row & 7) << 4)));
            }
#pragma unroll
            for (int mi = 0; mi < 2; ++mi)
#pragma unroll
                for (int ni = 0; ni < 4; ++ni)
                    acc[mi][ni] = __builtin_amdgcn_mfma_f32_16x16x32_bf16(af[mi], bfr[ni], acc[mi][ni], 0, 0, 0);
        }
        __syncthreads();
    }
    int fq = lane >> 4, fr = lane & 15;
#pragma unroll
    for (int mi = 0; mi < 2; ++mi)
#pragma unroll
        for (int ni = 0; ni < 4; ++ni) {
            int col = n0 + wc * 64 + ni * 16 + fr;
#pragma unroll
            for (int j = 0; j < 4; ++j) {
                int row = m0 + wr * 32 + mi * 16 + fq * 4 + j;
                Out[(size_t)row * 512 + col] = acc[mi][ni][j];
            }
        }
}

// ---------------- MFMA neighborhood attention ----------------
// Block = (4x8 query tile, head); grid (392,4); 4 waves.
// Phases: zero P/Vt -> stage K/Q/Vt/rpb -> S=Q.K^T (18 MFMA) -> S to LDS (aliases K)
//         -> 49-lane softmax scatter into dense P -> O=P.Vt (5 MFMA/wave).
__global__ __launch_bounds__(256) void na_mfma_kernel(
    const u16* __restrict__ Q, int qld,
    const u16* __restrict__ Kx, const u16* __restrict__ Vx, int kvld,
    const float* __restrict__ rpb, u16* __restrict__ Out)
{
    __shared__ float Sls[32 * 145];        // 18560B; aliased as Kls (144*40 u16 = 11520B)
    __shared__ u16 Qls[32 * 40];
    __shared__ u16 Pls[32 * 168];
    __shared__ u16 Vtls[32 * 168];
    __shared__ float rls[169];
    u16* Kls = reinterpret_cast<u16*>(Sls);

    int t = threadIdx.x, lane = t & 63, w = t >> 6;
    int h = blockIdx.y, blk = blockIdx.x;
    int b = blk / 98; int rem = blk - b * 98;
    int ti = rem / 7, tj = rem - ti * 7;
    int i0 = ti * 4, j0 = tj * 8;
    int r0 = min(max(i0 - 3, 0), 46), c0 = min(max(j0 - 3, 0), 42);
    int gbase = (b * 56 + r0) * 56 + c0;

    // phase 0: zero P and Vt (covers k-padding cols 140..167)
    {
        uint4 z = make_uint4(0, 0, 0, 0);
        uint4* pz = reinterpret_cast<uint4*>(Pls);
        uint4* vz = reinterpret_cast<uint4*>(Vtls);
        for (int i = t; i < 672; i += 256) { pz[i] = z; vz[i] = z; }
    }
    __syncthreads();

    // phase 1: stage K rows (0..139), V transposed, Q, rpb; zero K pad rows 140..143
    for (int idx = t; idx < 560; idx += 256) {
        int r = idx >> 2, c8 = (idx & 3) * 8;
        int ur = r / 14, uc = r - ur * 14;
        size_t g = (size_t)(gbase + ur * 56 + uc) * kvld + h * 32 + c8;
        *reinterpret_cast<bf16x8*>(Kls + r * 40 + c8) = *reinterpret_cast<const bf16x8*>(Kx + g);
        bf16x8 vv = *reinterpret_cast<const bf16x8*>(Vx + g);
#pragma unroll
        for (int e = 0; e < 8; ++e) Vtls[(c8 + e) * 168 + r] = (u16)vv[e];
    }
    if (t < 16) {
        int r = 140 + (t >> 2), c8 = (t & 3) * 8;
        bf16x8 z8 = {};
        *reinterpret_cast<bf16x8*>(Kls + r * 40 + c8) = z8;
    }
    if (t < 128) {
        int q = t >> 2, c8 = (t & 3) * 8;
        int qi = q >> 3, qj = q & 7;
        *reinterpret_cast<bf16x8*>(Qls + q * 40 + c8) =
            *reinterpret_cast<const bf16x8*>(Q + (size_t)((b * 56 + i0 + qi) * 56 + j0 + qj) * qld + h * 32 + c8);
    }
    if (t < 169) rls[t] = rpb[h * 169 + t];
    __syncthreads();

    // phase 2: S = Q.K^T ; wave w handles p-tiles {w, w+4, w+8}
    f32x4 sacc[3][2] = {};
#pragma unroll
    for (int pi = 0; pi < 3; ++pi) {
        int pt = w + pi * 4;
        if (pt < 9) {
            bf16x8 bfrag = *reinterpret_cast<const bf16x8*>(Kls + (pt * 16 + (lane & 15)) * 40 + (lane >> 4) * 8);
#pragma unroll
            for (int qt = 0; qt < 2; ++qt) {
                bf16x8 afrag = *reinterpret_cast<const bf16x8*>(Qls + (qt * 16 + (lane & 15)) * 40 + (lane >> 4) * 8);
                sacc[pi][qt] = __builtin_amdgcn_mfma_f32_16x16x32_bf16(afrag, bfrag, sacc[pi][qt], 0, 0, 0);
            }
        }
    }
    __syncthreads();   // all Kls reads done -> safe to overwrite with S
#pragma unroll
    for (int pi = 0; pi < 3; ++pi) {
        int pt = w + pi * 4;
        if (pt < 9) {
#pragma unroll
            for (int qt = 0; qt < 2; ++qt) {
                int p = pt * 16 + (lane & 15), qr = qt * 16 + (lane >> 4) * 4;
#pragma unroll
                for (int j = 0; j < 4; ++j) Sls[(qr + j) * 145 + p] = sacc[pi][qt][j];
            }
        }
    }
    __syncthreads();

    // phase 3: softmax, scatter bf16 into dense-zero P
    int ai = lane / 7, aj = lane - ai * 7;
    for (int qq = 0; qq < 8; ++qq) {
        int q = w * 8 + qq;
        int qi = q >> 3, qj = q & 7;
        int i = i0 + qi, j = j0 + qj;
        int si = min(max(i - 3, 0), 49), sj = min(max(j - 3, 0), 49);
        int pu_base = (si - r0) * 14 + (sj - c0);
        float s = -1e30f; int pu = 0;
        if (lane < 49) {
            pu = pu_base + ai * 14 + aj;
            s = Sls[q * 145 + pu] * 0.17677669529663687f
              + rls[(si - i + 6 + ai) * 13 + (sj - j + 6 + aj)];
        }
        float m = s;
#pragma unroll
        for (int o = 32; o > 0; o >>= 1) m = fmaxf(m, __shfl_xor(m, o));
        float e = (lane < 49) ? expf(s - m) : 0.f;
        float sum = e;
#pragma unroll
        for (int o = 32; o > 0; o >>= 1) sum += __shfl_xor(sum, o);
        if (lane < 49) Pls[q * 168 + pu] = rne_bf16(e / sum);
    }
    __syncthreads();

    // phase 4: O = P.Vt ; wave w -> (qtile, chtile)
    int qt = w >> 1, ct = w & 1;
    f32x4 oacc = {};
#pragma unroll
    for (int k = 0; k < 5; ++k) {
        bf16x8 pa = *reinterpret_cast<const bf16x8*>(Pls + (qt * 16 + (lane & 15)) * 168 + k * 32 + (lane >> 4) * 8);
        bf16x8 vb = *reinterpret_cast<const bf16x8*>(Vtls + (ct * 16 + (lane & 15)) * 168 + k * 32 + (lane >> 4) * 8);
        oacc = __builtin_amdgcn_mfma_f32_16x16x32_bf16(pa, vb, oacc, 0, 0, 0);
    }
    int ch = ct * 16 + (lane & 15);
#pragma unroll
    for (int j = 0; j < 4; ++j) {
        int q = qt * 16 + (lane >> 4) * 4 + j;
        int qi = q >> 3, qj = q & 7;
        Out[(size_t)((b * 56 + i0 + qi) * 56 + j0 + qj) * CH + h * 32 + ch] = rne_bf16(oacc[j]);
    }
}

// ---------------- final LayerNorm over 512, write f32 ----------------
__global__ __launch_bounds__(64) void ln512_out_kernel(const float* __restrict__ in,
    const float* __restrict__ g, const float* __restrict__ b, float* __restrict__ out)
{
    int p = blockIdx.x, lane = threadIdx.x;
    const float4* ip = reinterpret_cast<const float4*>(in + (size_t)p * 512);
    float4 v0 = ip[lane * 2], v1 = ip[lane * 2 + 1];
    float vals[8] = { v0.x, v0.y, v0.z, v0.w, v1.x, v1.y, v1.z, v1.w };
    float s = 0.f, sq = 0.f;
#pragma unroll
    for (int q = 0; q < 8; ++q) { s += vals[q]; sq += vals[q] * vals[q]; }
#pragma unroll
    for (int o = 32; o > 0; o >>= 1) { s += __shfl_xor(s, o); sq += __shfl_xor(sq, o); }
    float mean = s * (1.0f / 512.0f);
    float inv = rsqrtf(sq * (1.0f / 512.0f) - mean * mean + 1e-5f);
#pragma unroll
    for (int q = 0; q < 8; ++q) {
        int c = lane * 8 + q;
        out[(size_t)p * 512 + c] = (vals[q] - mean) * inv * g[c] + b[c];
    }
}

extern "C" void kernel_launch(void* const* d_in, const int* in_sizes, int n_in,
                              void* d_out, int out_size, void* d_ws, size_t ws_size,
                              hipStream_t stream)
{
    const float* X      = (const float*)d_in[0];
    const float* XM     = (const float*)d_in[1];
    const float* sa_n1g = (const float*)d_in[2];
    const float* sa_n1b = (const float*)d_in[3];
    const float* sa_qkvw= (const float*)d_in[4];
    const float* sa_qkvb= (const float*)d_in[5];
    const float* sa_rpb = (const float*)d_in[6];
    const float* sa_pw  = (const float*)d_in[7];
    const float* sa_pb  = (const float*)d_in[8];
    const float* sa_n2g = (const float*)d_in[9];
    const float* sa_n2b = (const float*)d_in[10];
    const float* sa_f1w = (const float*)d_in[11];
    const float* sa_f1b = (const float*)d_in[12];
    const float* sa_f2w = (const float*)d_in[13];
    const float* sa_f2b = (const float*)d_in[14];
    const float* cr_n1g = (const float*)d_in[15];
    const float* cr_n1b = (const float*)d_in[16];
    const float* cr_qw  = (const float*)d_in[17];
    const float* cr_qb  = (const float*)d_in[18];
    const float* cr_kvw = (const float*)d_in[19];
    const float* cr_kvb = (const float*)d_in[20];
    const float* cr_rpb = (const float*)d_in[21];
    const float* cr_pw  = (const float*)d_in[22];
    const float* cr_pb  = (const float*)d_in[23];
    const float* cr_n2g = (const float*)d_in[24];
    const float* cr_n2b = (const float*)d_in[25];
    const float* cr_f1w = (const float*)d_in[26];
    const float* cr_f1b = (const float*)d_in[27];
    const float* cr_f2w = (const float*)d_in[28];
    const float* cr_f2b = (const float*)d_in[29];
    const float* dconvw = (const float*)d_in[30];
    const float* ds_ng  = (const float*)d_in[31];
    const float* ds_nb  = (const float*)d_in[32];

    const size_t NC = (size_t)NPIX * CH;       // 1,605,632
    float* ws   = (float*)d_ws;
    float* xb   = ws;                          // [NPIX,128] f32 x state
    float* xcb  = xb + NC;                     // [NPIX,128] f32 x_cross state
    float* bigR = xcb + NC;                    // region, 2*NC f32: fc1 bf16 out OR conv f32 out
    u16* bigb   = (u16*)bigR;                  // [NPIX,512] bf16 (fc1)
    u16* hnb    = (u16*)(bigR + 2 * NC);       // [NPIX,128] bf16 LN out / conv in
    u16* attnb  = hnb + NC;                    // [NPIX,128] bf16 NA out / conv in
    u16* xcbbf  = attnb + NC;                  // [NPIX,128] bf16 copy of xcb
    u16* qkvb   = xcbbf + NC;                  // [NPIX,384] bf16 qkv / kv
    u16* bufQb  = qkvb + (size_t)NPIX * 384;   // [NPIX,128] bf16 cross q
    u16* wa     = bufQb + NC;                  // bf16 weight arena (~2.0M elems)

    // ---- weight arena layout + transpose descriptors ----
    TPack tp;
    int tile = 0, idx = 0;
    u16* p = wa;
    u16* qkvt[2]; u16* pwt[2]; u16* f1t[2]; u16* f2t[2];
    u16* qt[2];   u16* kvt[2]; u16* cpt[2]; u16* cf1t[2];
    u16* cf2t[2]; u16* convt;
    auto add = [&](const float* s, u16*& dst, int K, int N) {
        dst = p;
        tp.d[idx].src = s; tp.d[idx].dst = p; tp.d[idx].K = K; tp.d[idx].N = N; tp.d[idx].tile0 = tile;
        tile += (K / 32) * (N / 32); p += (size_t)K * N; ++idx;
    };
    for (int l = 0; l < 2; ++l) add(sa_qkvw + (size_t)l * 128 * 384, qkvt[l], 128, 384);
    for (int l = 0; l < 2; ++l) add(sa_pw   + (size_t)l * 128 * 128, pwt[l],  128, 128);
    for (int l = 0; l < 2; ++l) add(sa_f1w  + (size_t)l * 128 * 512, f1t[l],  128, 512);
    for (int l = 0; l < 2; ++l) add(sa_f2w  + (size_t)l * 512 * 128, f2t[l],  512, 128);
    for (int l = 0; l < 2; ++l) add(cr_qw   + (size_t)l * 128 * 128, qt[l],   128, 128);
    for (int l = 0; l < 2; ++l) add(cr_kvw  + (size_t)l * 128 * 256, kvt[l],  128, 256);
    for (int l = 0; l < 2; ++l) add(cr_pw   + (size_t)l * 128 * 128, cpt[l],  128, 128);
    for (int l = 0; l < 2; ++l) add(cr_f1w  + (size_t)l * 128 * 512, cf1t[l], 128, 512);
    for (int l = 0; l < 2; ++l) add(cr_f2w  + (size_t)l * 512 * 128, cf2t[l], 512, 128);
    add(dconvw, convt, 2304, 512);

    wtrans_kernel<<<tile, 256, 0, stream>>>(tp);

    const int n4 = NPIX * CH / 4;
    dup_kernel<<<(n4 + 255) / 256, 256, 0, stream>>>(X, xb, xcb, n4);

    // ---- self-attention layers ----
    for (int l = 0; l < 2; ++l) {
        ln128_kernel<<<NPIX, 64, 0, stream>>>(xb, sa_n1g + l * CH, sa_n1b + l * CH, hnb);
        mfma_gemm_kernel<128, 3><<<dim3(NPIX / 128, 3), 256, 0, stream>>>(
            hnb, qkvt[l], sa_qkvb + l * 384, nullptr, nullptr, qkvb, NPIX, 384, 128);
        na_mfma_kernel<<<dim3(392, 4), 256, 0, stream>>>(qkvb, 384, qkvb + 128, qkvb + 256, 384,
                                                         sa_rpb + l * HEADS * 169, attnb);
        mfma_gemm_kernel<64, 2><<<dim3(NPIX / 128, 2), 256, 0, stream>>>(
            attnb, pwt[l], sa_pb + l * CH, xb, xb, nullptr, NPIX, 128, 128);
        ln128_kernel<<<NPIX, 64, 0, stream>>>(xb, sa_n2g + l * CH, sa_n2b + l * CH, hnb);
        mfma_gemm_kernel<128, 1><<<dim3(NPIX / 128, 4), 256, 0, stream>>>(
            hnb, f1t[l], sa_f1b + l * HID, nullptr, nullptr, bigb, NPIX, 512, 128);
        mfma_gemm_kernel<64, 2><<<dim3(NPIX / 128, 2), 256, 0, stream>>>(
            bigb, f2t[l], sa_f2b + l * CH, xb, xb, nullptr, NPIX, 128, 512);
    }

    // ---- cross layers ----
    for (int l = 0; l < 2; ++l) {
        ln128_kernel<<<NPIX, 64, 0, stream>>>(XM, cr_n1g + l * CH, cr_n1b + l * CH, hnb);
        cvtb_kernel<<<(n4 + 255) / 256, 256, 0, stream>>>(xcb, xcbbf, n4);
        mfma_gemm_kernel<64, 3><<<dim3(NPIX / 128, 2), 256, 0, stream>>>(
            xcbbf, qt[l], cr_qb + l * CH, nullptr, nullptr, bufQb, NPIX, 128, 128);
        mfma_gemm_kernel<128, 3><<<dim3(NPIX / 128, 2), 256, 0, stream>>>(
            hnb, kvt[l], cr_kvb + l * 256, nullptr, nullptr, qkvb, NPIX, 256, 128);
        na_mfma_kernel<<<dim3(392, 4), 256, 0, stream>>>(bufQb, 128, qkvb, qkvb + 128, 256,
                                                         cr_rpb + l * HEADS * 169, attnb);
        mfma_gemm_kernel<64, 2><<<dim3(NPIX / 128, 2), 256, 0, stream>>>(
            attnb, cpt[l], cr_pb + l * CH, XM, xcb, nullptr, NPIX, 128, 128);
        ln128_kernel<<<NPIX, 64, 0, stream>>>(xcb, cr_n2g + l * CH, cr_n2b + l * CH, hnb);
        mfma_gemm_kernel<128, 1><<<dim3(NPIX / 128, 4), 256, 0, stream>>>(
            hnb, cf1t[l], cr_f1b + l * HID, nullptr, nullptr, bigb, NPIX, 512, 128);
        mfma_gemm_kernel<64, 2><<<dim3(NPIX / 128, 2), 256, 0, stream>>>(
            bigb, cf2t[l], cr_f2b + l * CH, xcb, xcb, nullptr, NPIX, 128, 512);
    }

    // ---- downsample conv (MFMA implicit GEMM) + final LN ----
    cvtb_kernel<<<(n4 + 255) / 256, 256, 0, stream>>>(xb, hnb, n4);
    cvtb_kernel<<<(n4 + 255) / 256, 256, 0, stream>>>(xcb, attnb, n4);
    conv_mfma_kernel<<<dim3(3136 / 64, 4), 256, 0, stream>>>(hnb, attnb, convt, bigR);
    ln512_out_kernel<<<3136, 64, 0, stream>>>(bigR, ds_ng, ds_nb, (float*)d_out);
}

// Round 8
// 339.904 us; speedup vs baseline: 4.8899x; 1.0752x over previous
//
#include <hip/hip_runtime.h>
#include <math.h>

#define NPIX 12544   // B*H*W = 4*56*56
#define CH   128
#define HEADS 4
#define HD   32
#define KS   7
#define HID  512
#define HH   56
#define WW   56

typedef __attribute__((ext_vector_type(8))) short bf16x8;
typedef __attribute__((ext_vector_type(4))) float f32x4;
typedef unsigned short u16;

__device__ inline float gelu_f(float x) { return 0.5f * x * (1.0f + erff(x * 0.70710678118654752f)); }

__device__ inline u16 rne_bf16(float x) {
    unsigned u = __float_as_uint(x);
    return (u16)((u + 0x7fffu + ((u >> 16) & 1u)) >> 16);
}
__device__ inline float bf2f(u16 u) {
    return __uint_as_float(((unsigned)u) << 16);
}

// ---------------- copy f32 into two state buffers + bf16 mirror of x_cross ----------------
__global__ __launch_bounds__(256) void dup_kernel(const float* __restrict__ in,
    float* __restrict__ o1, float* __restrict__ o2, u16* __restrict__ ob, int n4)
{
    int i = blockIdx.x * 256 + threadIdx.x;
    if (i < n4) {
        float4 v = reinterpret_cast<const float4*>(in)[i];
        reinterpret_cast<float4*>(o1)[i] = v;
        reinterpret_cast<float4*>(o2)[i] = v;
        ushort4 o;
        o.x = rne_bf16(v.x); o.y = rne_bf16(v.y); o.z = rne_bf16(v.z); o.w = rne_bf16(v.w);
        reinterpret_cast<ushort4*>(ob)[i] = o;
    }
}

// ---------------- weight transpose + convert: f32 [K][N] -> bf16 [N][K] ----------------
struct TDesc { const float* src; u16* dst; int K; int N; int tile0; };
struct TPack { TDesc d[19]; };

__global__ __launch_bounds__(256) void wtrans_kernel(TPack p)
{
    __shared__ float tl[32][33];
    int tile = blockIdx.x;
    int i = 0;
#pragma unroll 1
    while (i < 18 && tile >= p.d[i + 1].tile0) ++i;
    TDesc d = p.d[i];
    int local = tile - d.tile0;
    int ktiles = d.K >> 5;
    int lk = local % ktiles, ln_ = local / ktiles;
    int k0 = lk * 32, n0 = ln_ * 32;
    int tx = threadIdx.x & 31, ty = threadIdx.x >> 5;
#pragma unroll
    for (int r = 0; r < 4; ++r) {
        int row = ty * 4 + r;
        tl[row][tx] = d.src[(size_t)(k0 + row) * d.N + n0 + tx];
    }
    __syncthreads();
#pragma unroll
    for (int r = 0; r < 4; ++r) {
        int row = ty * 4 + r;
        d.dst[(size_t)(n0 + row) * d.K + k0 + tx] = rne_bf16(tl[tx][row]);
    }
}

// ---------------- LayerNorm over C=128, one wave per row, bf16 out ----------------
__global__ __launch_bounds__(64) void ln128_kernel(const float* __restrict__ in,
    const float* __restrict__ g, const float* __restrict__ b, u16* __restrict__ out)
{
    int p = blockIdx.x, lane = threadIdx.x;
    float2 v = reinterpret_cast<const float2*>(in + (size_t)p * CH)[lane];
    float s = v.x + v.y, sq = v.x * v.x + v.y * v.y;
#pragma unroll
    for (int o = 32; o > 0; o >>= 1) { s += __shfl_xor(s, o); sq += __shfl_xor(sq, o); }
    float mean = s * (1.0f / CH);
    float inv = rsqrtf(sq * (1.0f / CH) - mean * mean + 1e-5f);
    float2 gg = reinterpret_cast<const float2*>(g)[lane];
    float2 bb = reinterpret_cast<const float2*>(b)[lane];
    ushort2 o;
    o.x = rne_bf16((v.x - mean) * inv * gg.x + bb.x);
    o.y = rne_bf16((v.y - mean) * inv * gg.y + bb.y);
    reinterpret_cast<ushort2*>(out + (size_t)p * CH)[lane] = o;
}

// ---------------- MFMA GEMM: A bf16 [M][K], Bt bf16 [N][K] -> C [M][N] ----------------
// MODE 0: f32 = acc+bias            MODE 1: bf16 = gelu(acc+bias)
// MODE 2: f32 = acc+bias+res       MODE 3: bf16 = acc+bias
// MODE 4: f32 = acc+bias+res AND bf16 mirror
template<int BN, int MODE>
__global__ __launch_bounds__(256) void mfma_gemm_kernel(
    const u16* __restrict__ A, const u16* __restrict__ Bt,
    const float* __restrict__ bias, const float* __restrict__ res,
    float* __restrict__ Cf, u16* __restrict__ Cb,
    int M, int N, int K)
{
    constexpr int MF = 4, NF = BN / 32;
    __shared__ u16 Als[128 * 64];
    __shared__ u16 Bls[BN * 64];
    char* alsb = reinterpret_cast<char*>(Als);
    char* blsb = reinterpret_cast<char*>(Bls);
    int t = threadIdx.x;
    int m0 = blockIdx.x * 128, n0 = blockIdx.y * BN;
    int lane = t & 63, w = t >> 6;
    int wr = w >> 1, wc = w & 1;
    f32x4 acc[MF][NF] = {};
    for (int k0 = 0; k0 < K; k0 += 64) {
#pragma unroll
        for (int i = 0; i < 4; ++i) {
            int s = t + i * 256, row = s >> 3, ch = (s & 7) * 8;
            bf16x8 v = *reinterpret_cast<const bf16x8*>(A + (size_t)(m0 + row) * K + k0 + ch);
            *reinterpret_cast<bf16x8*>(alsb + row * 128 + ((ch * 2) ^ ((row & 7) << 4))) = v;
        }
#pragma unroll
        for (int i = 0; i < NF; ++i) {
            int s = t + i * 256, row = s >> 3, ch = (s & 7) * 8;
            bf16x8 v = *reinterpret_cast<const bf16x8*>(Bt + (size_t)(n0 + row) * K + k0 + ch);
            *reinterpret_cast<bf16x8*>(blsb + row * 128 + ((ch * 2) ^ ((row & 7) << 4))) = v;
        }
        __syncthreads();
#pragma unroll
        for (int kk = 0; kk < 2; ++kk) {
            int kb = kk * 64 + (lane >> 4) * 16;
            bf16x8 af[MF], bfr[NF];
#pragma unroll
            for (int mi = 0; mi < MF; ++mi) {
                int row = wr * 64 + mi * 16 + (lane & 15);
                af[mi] = *reinterpret_cast<const bf16x8*>(alsb + row * 128 + (kb ^ ((row & 7) << 4)));
            }
#pragma unroll
            for (int ni = 0; ni < NF; ++ni) {
                int row = wc * (BN / 2) + ni * 16 + (lane & 15);
                bfr[ni] = *reinterpret_cast<const bf16x8*>(blsb + row * 128 + (kb ^ ((row & 7) << 4)));
            }
#pragma unroll
            for (int mi = 0; mi < MF; ++mi)
#pragma unroll
                for (int ni = 0; ni < NF; ++ni)
                    acc[mi][ni] = __builtin_amdgcn_mfma_f32_16x16x32_bf16(af[mi], bfr[ni], acc[mi][ni], 0, 0, 0);
        }
        __syncthreads();
    }
    int fq = lane >> 4, fr = lane & 15;
#pragma unroll
    for (int mi = 0; mi < MF; ++mi) {
#pragma unroll
        for (int ni = 0; ni < NF; ++ni) {
            int col = n0 + wc * (BN / 2) + ni * 16 + fr;
            float bv = bias[col];
#pragma unroll
            for (int j = 0; j < 4; ++j) {
                int row = m0 + wr * 64 + mi * 16 + fq * 4 + j;
                float v = acc[mi][ni][j] + bv;
                if constexpr (MODE == 1) {
                    Cb[(size_t)row * N + col] = rne_bf16(gelu_f(v));
                } else if constexpr (MODE == 2) {
                    Cf[(size_t)row * N + col] = v + res[(size_t)row * N + col];
                } else if constexpr (MODE == 3) {
                    Cb[(size_t)row * N + col] = rne_bf16(v);
                } else if constexpr (MODE == 4) {
                    float r2 = v + res[(size_t)row * N + col];
                    Cf[(size_t)row * N + col] = r2;
                    Cb[(size_t)row * N + col] = rne_bf16(r2);
                } else {
                    Cf[(size_t)row * N + col] = v;
                }
            }
        }
    }
}

// ---------------- conv as MFMA implicit GEMM: M=3136 (BM=32), N=512 (BN=64), K=2304 ----------------
__global__ __launch_bounds__(256) void conv_mfma_kernel(
    const u16* __restrict__ Xb, const u16* __restrict__ Xc,
    const u16* __restrict__ Wt, float* __restrict__ Out)
{
    __shared__ u16 Als[32 * 64];
    __shared__ u16 Bls[64 * 64];
    char* alsb = reinterpret_cast<char*>(Als);
    char* blsb = reinterpret_cast<char*>(Bls);
    int t = threadIdx.x;
    int m0 = blockIdx.x * 32, n0 = blockIdx.y * 64;
    int lane = t & 63, w = t >> 6, wr = w >> 1, wc = w & 1;

    // A staging: one slot per thread (32 rows x 8 chunks)
    int arow = t >> 3, ach = (t & 7) * 8;
    int pm = m0 + arow;
    int b = pm / 784; int rem = pm - b * 784;
    int oi = rem / 28, oj = rem - oi * 28;
    int pb = b * 56, ib = 2 * oi - 1, jb = 2 * oj - 1;

    f32x4 acc[2] = {};
    for (int k0 = 0; k0 < 2304; k0 += 64) {
        {
            int k = k0 + ach;
            int tap = k >> 8, c = k & 255;
            int ky = (tap * 11) >> 5, kx = tap - ky * 3;
            int ii = ib + ky, jj = jb + kx;
            bf16x8 v = {};
            if ((unsigned)ii < 56u && (unsigned)jj < 56u) {
                const u16* src = (c < 128) ? Xb : Xc;
                v = *reinterpret_cast<const bf16x8*>(src + (size_t)((pb + ii) * 56 + jj) * 128 + (c & 127));
            }
            *reinterpret_cast<bf16x8*>(alsb + arow * 128 + ((ach * 2) ^ ((arow & 7) << 4))) = v;
        }
#pragma unroll
        for (int i = 0; i < 2; ++i) {
            int s = t + i * 256, row = s >> 3, ch = (s & 7) * 8;
            bf16x8 v = *reinterpret_cast<const bf16x8*>(Wt + (size_t)(n0 + row) * 2304 + k0 + ch);
            *reinterpret_cast<bf16x8*>(blsb + row * 128 + ((ch * 2) ^ ((row & 7) << 4))) = v;
        }
        __syncthreads();
#pragma unroll
        for (int kk = 0; kk < 2; ++kk) {
            int kb = kk * 64 + (lane >> 4) * 16;
            int row_a = wr * 16 + (lane & 15);
            bf16x8 af = *reinterpret_cast<const bf16x8*>(alsb + row_a * 128 + (kb ^ ((row_a & 7) << 4)));
#pragma unroll
            for (int ni = 0; ni < 2; ++ni) {
                int row = wc * 32 + ni * 16 + (lane & 15);
                bf16x8 bfr = *reinterpret_cast<const bf16x8*>(blsb + row * 128 + (kb ^ ((row & 7) << 4)));
                acc[ni] = __builtin_amdgcn_mfma_f32_16x16x32_bf16(af, bfr, acc[ni], 0, 0, 0);
            }
        }
        __syncthreads();
    }
    int fq = lane >> 4, fr = lane & 15;
#pragma unroll
    for (int ni = 0; ni < 2; ++ni) {
        int col = n0 + wc * 32 + ni * 16 + fr;
#pragma unroll
        for (int j = 0; j < 4; ++j) {
            int row = m0 + wr * 16 + fq * 4 + j;
            Out[(size_t)row * 512 + col] = acc[ni][j];
        }
    }
}

// ---------------- MFMA neighborhood attention ----------------
__global__ __launch_bounds__(256) void na_mfma_kernel(
    const u16* __restrict__ Q, int qld,
    const u16* __restrict__ Kx, const u16* __restrict__ Vx, int kvld,
    const float* __restrict__ rpb, u16* __restrict__ Out)
{
    __shared__ float Sls[32 * 145];        // aliased as Kls (144*40 u16)
    __shared__ u16 Qls[32 * 40];
    __shared__ u16 Pls[32 * 168];
    __shared__ u16 Vtls[32 * 168];
    __shared__ float rls[169];
    u16* Kls = reinterpret_cast<u16*>(Sls);

    int t = threadIdx.x, lane = t & 63, w = t >> 6;
    int h = blockIdx.y, blk = blockIdx.x;
    int b = blk / 98; int rem = blk - b * 98;
    int ti = rem / 7, tj = rem - ti * 7;
    int i0 = ti * 4, j0 = tj * 8;
    int r0 = min(max(i0 - 3, 0), 46), c0 = min(max(j0 - 3, 0), 42);
    int gbase = (b * 56 + r0) * 56 + c0;

    {
        uint4 z = make_uint4(0, 0, 0, 0);
        uint4* pz = reinterpret_cast<uint4*>(Pls);
        uint4* vz = reinterpret_cast<uint4*>(Vtls);
        for (int i = t; i < 672; i += 256) { pz[i] = z; vz[i] = z; }
    }
    __syncthreads();

    for (int idx = t; idx < 560; idx += 256) {
        int r = idx >> 2, c8 = (idx & 3) * 8;
        int ur = r / 14, uc = r - ur * 14;
        size_t g = (size_t)(gbase + ur * 56 + uc) * kvld + h * 32 + c8;
        *reinterpret_cast<bf16x8*>(Kls + r * 40 + c8) = *reinterpret_cast<const bf16x8*>(Kx + g);
        bf16x8 vv = *reinterpret_cast<const bf16x8*>(Vx + g);
#pragma unroll
        for (int e = 0; e < 8; ++e) Vtls[(c8 + e) * 168 + r] = (u16)vv[e];
    }
    if (t < 16) {
        int r = 140 + (t >> 2), c8 = (t & 3) * 8;
        bf16x8 z8 = {};
        *reinterpret_cast<bf16x8*>(Kls + r * 40 + c8) = z8;
    }
    if (t < 128) {
        int q = t >> 2, c8 = (t & 3) * 8;
        int qi = q >> 3, qj = q & 7;
        *reinterpret_cast<bf16x8*>(Qls + q * 40 + c8) =
            *reinterpret_cast<const bf16x8*>(Q + (size_t)((b * 56 + i0 + qi) * 56 + j0 + qj) * qld + h * 32 + c8);
    }
    if (t < 169) rls[t] = rpb[h * 169 + t];
    __syncthreads();

    f32x4 sacc[3][2] = {};
#pragma unroll
    for (int pi = 0; pi < 3; ++pi) {
        int pt = w + pi * 4;
        if (pt < 9) {
            bf16x8 bfrag = *reinterpret_cast<const bf16x8*>(Kls + (pt * 16 + (lane & 15)) * 40 + (lane >> 4) * 8);
#pragma unroll
            for (int qt = 0; qt < 2; ++qt) {
                bf16x8 afrag = *reinterpret_cast<const bf16x8*>(Qls + (qt * 16 + (lane & 15)) * 40 + (lane >> 4) * 8);
                sacc[pi][qt] = __builtin_amdgcn_mfma_f32_16x16x32_bf16(afrag, bfrag, sacc[pi][qt], 0, 0, 0);
            }
        }
    }
    __syncthreads();
#pragma unroll
    for (int pi = 0; pi < 3; ++pi) {
        int pt = w + pi * 4;
        if (pt < 9) {
#pragma unroll
            for (int qt = 0; qt < 2; ++qt) {
                int p = pt * 16 + (lane & 15), qr = qt * 16 + (lane >> 4) * 4;
#pragma unroll
                for (int j = 0; j < 4; ++j) Sls[(qr + j) * 145 + p] = sacc[pi][qt][j];
            }
        }
    }
    __syncthreads();

    int ai = lane / 7, aj = lane - ai * 7;
    for (int qq = 0; qq < 8; ++qq) {
        int q = w * 8 + qq;
        int qi = q >> 3, qj = q & 7;
        int i = i0 + qi, j = j0 + qj;
        int si = min(max(i - 3, 0), 49), sj = min(max(j - 3, 0), 49);
        int pu_base = (si - r0) * 14 + (sj - c0);
        float s = -1e30f; int pu = 0;
        if (lane < 49) {
            pu = pu_base + ai * 14 + aj;
            s = Sls[q * 145 + pu] * 0.17677669529663687f
              + rls[(si - i + 6 + ai) * 13 + (sj - j + 6 + aj)];
        }
        float m = s;
#pragma unroll
        for (int o = 32; o > 0; o >>= 1) m = fmaxf(m, __shfl_xor(m, o));
        float e = (lane < 49) ? expf(s - m) : 0.f;
        float sum = e;
#pragma unroll
        for (int o = 32; o > 0; o >>= 1) sum += __shfl_xor(sum, o);
        if (lane < 49) Pls[q * 168 + pu] = rne_bf16(e / sum);
    }
    __syncthreads();

    int qt = w >> 1, ct = w & 1;
    f32x4 oacc = {};
#pragma unroll
    for (int k = 0; k < 5; ++k) {
        bf16x8 pa = *reinterpret_cast<const bf16x8*>(Pls + (qt * 16 + (lane & 15)) * 168 + k * 32 + (lane >> 4) * 8);
        bf16x8 vb = *reinterpret_cast<const bf16x8*>(Vtls + (ct * 16 + (lane & 15)) * 168 + k * 32 + (lane >> 4) * 8);
        oacc = __builtin_amdgcn_mfma_f32_16x16x32_bf16(pa, vb, oacc, 0, 0, 0);
    }
    int ch = ct * 16 + (lane & 15);
#pragma unroll
    for (int j = 0; j < 4; ++j) {
        int q = qt * 16 + (lane >> 4) * 4 + j;
        int qi = q >> 3, qj = q & 7;
        Out[(size_t)((b * 56 + i0 + qi) * 56 + j0 + qj) * CH + h * 32 + ch] = rne_bf16(oacc[j]);
    }
}

// ---------------- final LayerNorm over 512, write f32 ----------------
__global__ __launch_bounds__(64) void ln512_out_kernel(const float* __restrict__ in,
    const float* __restrict__ g, const float* __restrict__ b, float* __restrict__ out)
{
    int p = blockIdx.x, lane = threadIdx.x;
    const float4* ip = reinterpret_cast<const float4*>(in + (size_t)p * 512);
    float4 v0 = ip[lane * 2], v1 = ip[lane * 2 + 1];
    float vals[8] = { v0.x, v0.y, v0.z, v0.w, v1.x, v1.y, v1.z, v1.w };
    float s = 0.f, sq = 0.f;
#pragma unroll
    for (int q = 0; q < 8; ++q) { s += vals[q]; sq += vals[q] * vals[q]; }
#pragma unroll
    for (int o = 32; o > 0; o >>= 1) { s += __shfl_xor(s, o); sq += __shfl_xor(sq, o); }
    float mean = s * (1.0f / 512.0f);
    float inv = rsqrtf(sq * (1.0f / 512.0f) - mean * mean + 1e-5f);
#pragma unroll
    for (int q = 0; q < 8; ++q) {
        int c = lane * 8 + q;
        out[(size_t)p * 512 + c] = (vals[q] - mean) * inv * g[c] + b[c];
    }
}

extern "C" void kernel_launch(void* const* d_in, const int* in_sizes, int n_in,
                              void* d_out, int out_size, void* d_ws, size_t ws_size,
                              hipStream_t stream)
{
    const float* X      = (const float*)d_in[0];
    const float* XM     = (const float*)d_in[1];
    const float* sa_n1g = (const float*)d_in[2];
    const float* sa_n1b = (const float*)d_in[3];
    const float* sa_qkvw= (const float*)d_in[4];
    const float* sa_qkvb= (const float*)d_in[5];
    const float* sa_rpb = (const float*)d_in[6];
    const float* sa_pw  = (const float*)d_in[7];
    const float* sa_pb  = (const float*)d_in[8];
    const float* sa_n2g = (const float*)d_in[9];
    const float* sa_n2b = (const float*)d_in[10];
    const float* sa_f1w = (const float*)d_in[11];
    const float* sa_f1b = (const float*)d_in[12];
    const float* sa_f2w = (const float*)d_in[13];
    const float* sa_f2b = (const float*)d_in[14];
    const float* cr_n1g = (const float*)d_in[15];
    const float* cr_n1b = (const float*)d_in[16];
    const float* cr_qw  = (const float*)d_in[17];
    const float* cr_qb  = (const float*)d_in[18];
    const float* cr_kvw = (const float*)d_in[19];
    const float* cr_kvb = (const float*)d_in[20];
    const float* cr_rpb = (const float*)d_in[21];
    const float* cr_pw  = (const float*)d_in[22];
    const float* cr_pb  = (const float*)d_in[23];
    const float* cr_n2g = (const float*)d_in[24];
    const float* cr_n2b = (const float*)d_in[25];
    const float* cr_f1w = (const float*)d_in[26];
    const float* cr_f1b = (const float*)d_in[27];
    const float* cr_f2w = (const float*)d_in[28];
    const float* cr_f2b = (const float*)d_in[29];
    const float* dconvw = (const float*)d_in[30];
    const float* ds_ng  = (const float*)d_in[31];
    const float* ds_nb  = (const float*)d_in[32];

    const size_t NC = (size_t)NPIX * CH;       // 1,605,632
    float* ws   = (float*)d_ws;
    float* xb   = ws;                          // [NPIX,128] f32 x state
    float* xcb  = xb + NC;                     // [NPIX,128] f32 x_cross state
    float* bigR = xcb + NC;                    // region, 2*NC f32: fc1 bf16 out OR conv f32 out
    u16* bigb   = (u16*)bigR;                  // [NPIX,512] bf16 (fc1)
    u16* hnb    = (u16*)(bigR + 2 * NC);       // [NPIX,128] bf16 LN out
    u16* attnb  = hnb + NC;                    // [NPIX,128] bf16 NA out
    u16* xcbbf  = attnb + NC;                  // [NPIX,128] bf16 mirror of xcb state
    u16* xbbf   = xcbbf + NC;                  // [NPIX,128] bf16 mirror of xb (for conv)
    u16* qkvb   = xbbf + NC;                   // [NPIX,384] bf16 qkv / kv
    u16* bufQb  = qkvb + (size_t)NPIX * 384;   // [NPIX,128] bf16 cross q
    u16* wa     = bufQb + NC;                  // bf16 weight arena (~2.0M elems)

    // ---- weight arena layout + transpose descriptors ----
    TPack tp;
    int tile = 0, idx = 0;
    u16* p = wa;
    u16* qkvt[2]; u16* pwt[2]; u16* f1t[2]; u16* f2t[2];
    u16* qt[2];   u16* kvt[2]; u16* cpt[2]; u16* cf1t[2];
    u16* cf2t[2]; u16* convt;
    auto add = [&](const float* s, u16*& dst, int K, int N) {
        dst = p;
        tp.d[idx].src = s; tp.d[idx].dst = p; tp.d[idx].K = K; tp.d[idx].N = N; tp.d[idx].tile0 = tile;
        tile += (K / 32) * (N / 32); p += (size_t)K * N; ++idx;
    };
    for (int l = 0; l < 2; ++l) add(sa_qkvw + (size_t)l * 128 * 384, qkvt[l], 128, 384);
    for (int l = 0; l < 2; ++l) add(sa_pw   + (size_t)l * 128 * 128, pwt[l],  128, 128);
    for (int l = 0; l < 2; ++l) add(sa_f1w  + (size_t)l * 128 * 512, f1t[l],  128, 512);
    for (int l = 0; l < 2; ++l) add(sa_f2w  + (size_t)l * 512 * 128, f2t[l],  512, 128);
    for (int l = 0; l < 2; ++l) add(cr_qw   + (size_t)l * 128 * 128, qt[l],   128, 128);
    for (int l = 0; l < 2; ++l) add(cr_kvw  + (size_t)l * 128 * 256, kvt[l],  128, 256);
    for (int l = 0; l < 2; ++l) add(cr_pw   + (size_t)l * 128 * 128, cpt[l],  128, 128);
    for (int l = 0; l < 2; ++l) add(cr_f1w  + (size_t)l * 128 * 512, cf1t[l], 128, 512);
    for (int l = 0; l < 2; ++l) add(cr_f2w  + (size_t)l * 512 * 128, cf2t[l], 512, 128);
    add(dconvw, convt, 2304, 512);

    wtrans_kernel<<<tile, 256, 0, stream>>>(tp);

    const int n4 = NPIX * CH / 4;
    dup_kernel<<<(n4 + 255) / 256, 256, 0, stream>>>(X, xb, xcb, xcbbf, n4);

    // ---- self-attention layers ----
    for (int l = 0; l < 2; ++l) {
        ln128_kernel<<<NPIX, 64, 0, stream>>>(xb, sa_n1g + l * CH, sa_n1b + l * CH, hnb);
        mfma_gemm_kernel<128, 3><<<dim3(NPIX / 128, 3), 256, 0, stream>>>(
            hnb, qkvt[l], sa_qkvb + l * 384, nullptr, nullptr, qkvb, NPIX, 384, 128);
        na_mfma_kernel<<<dim3(392, 4), 256, 0, stream>>>(qkvb, 384, qkvb + 128, qkvb + 256, 384,
                                                         sa_rpb + l * HEADS * 169, attnb);
        mfma_gemm_kernel<64, 2><<<dim3(NPIX / 128, 2), 256, 0, stream>>>(
            attnb, pwt[l], sa_pb + l * CH, xb, xb, nullptr, NPIX, 128, 128);
        ln128_kernel<<<NPIX, 64, 0, stream>>>(xb, sa_n2g + l * CH, sa_n2b + l * CH, hnb);
        mfma_gemm_kernel<128, 1><<<dim3(NPIX / 128, 4), 256, 0, stream>>>(
            hnb, f1t[l], sa_f1b + l * HID, nullptr, nullptr, bigb, NPIX, 512, 128);
        mfma_gemm_kernel<64, 4><<<dim3(NPIX / 128, 2), 256, 0, stream>>>(
            bigb, f2t[l], sa_f2b + l * CH, xb, xb, xbbf, NPIX, 128, 512);
    }

    // ---- cross layers ----
    for (int l = 0; l < 2; ++l) {
        ln128_kernel<<<NPIX, 64, 0, stream>>>(XM, cr_n1g + l * CH, cr_n1b + l * CH, hnb);
        mfma_gemm_kernel<64, 3><<<dim3(NPIX / 128, 2), 256, 0, stream>>>(
            xcbbf, qt[l], cr_qb + l * CH, nullptr, nullptr, bufQb, NPIX, 128, 128);
        mfma_gemm_kernel<128, 3><<<dim3(NPIX / 128, 2), 256, 0, stream>>>(
            hnb, kvt[l], cr_kvb + l * 256, nullptr, nullptr, qkvb, NPIX, 256, 128);
        na_mfma_kernel<<<dim3(392, 4), 256, 0, stream>>>(bufQb, 128, qkvb, qkvb + 128, 256,
                                                         cr_rpb + l * HEADS * 169, attnb);
        mfma_gemm_kernel<64, 2><<<dim3(NPIX / 128, 2), 256, 0, stream>>>(
            attnb, cpt[l], cr_pb + l * CH, XM, xcb, nullptr, NPIX, 128, 128);
        ln128_kernel<<<NPIX, 64, 0, stream>>>(xcb, cr_n2g + l * CH, cr_n2b + l * CH, hnb);
        mfma_gemm_kernel<128, 1><<<dim3(NPIX / 128, 4), 256, 0, stream>>>(
            hnb, cf1t[l], cr_f1b + l * HID, nullptr, nullptr, bigb, NPIX, 512, 128);
        mfma_gemm_kernel<64, 4><<<dim3(NPIX / 128, 2), 256, 0, stream>>>(
            bigb, cf2t[l], cr_f2b + l * CH, xcb, xcb, xcbbf, NPIX, 128, 512);
    }

    // ---- downsample conv (MFMA implicit GEMM) + final LN ----
    conv_mfma_kernel<<<dim3(3136 / 32, 512 / 64), 256, 0, stream>>>(xbbf, xcbbf, convt, bigR);
    ln512_out_kernel<<<3136, 64, 0, stream>>>(bigR, ds_ng, ds_nb, (float*)d_out);
}

// Round 9
// 296.886 us; speedup vs baseline: 5.5984x; 1.1449x over previous
//
#include <hip/hip_runtime.h>
#include <math.h>

#define NPIX 12544   // B*H*W = 4*56*56
#define CH   128
#define HEADS 4
#define HD   32
#define KS   7
#define HID  512
#define HH   56
#define WW   56

typedef __attribute__((ext_vector_type(8))) short bf16x8;
typedef __attribute__((ext_vector_type(4))) float f32x4;
typedef unsigned short u16;

__device__ inline float gelu_f(float x) { return 0.5f * x * (1.0f + erff(x * 0.70710678118654752f)); }

__device__ inline u16 rne_bf16(float x) {
    unsigned u = __float_as_uint(x);
    return (u16)((u + 0x7fffu + ((u >> 16) & 1u)) >> 16);
}
__device__ inline float bf2f(u16 u) {
    return __uint_as_float(((unsigned)u) << 16);
}

// ---------------- copy f32 into two state buffers + bf16 mirror of x_cross ----------------
__global__ __launch_bounds__(256) void dup_kernel(const float* __restrict__ in,
    float* __restrict__ o1, float* __restrict__ o2, u16* __restrict__ ob, int n4)
{
    int i = blockIdx.x * 256 + threadIdx.x;
    if (i < n4) {
        float4 v = reinterpret_cast<const float4*>(in)[i];
        reinterpret_cast<float4*>(o1)[i] = v;
        reinterpret_cast<float4*>(o2)[i] = v;
        ushort4 o;
        o.x = rne_bf16(v.x); o.y = rne_bf16(v.y); o.z = rne_bf16(v.z); o.w = rne_bf16(v.w);
        reinterpret_cast<ushort4*>(ob)[i] = o;
    }
}

// ---------------- weight transpose + convert: f32 [K][N] -> bf16 [N][K] ----------------
struct TDesc { const float* src; u16* dst; int K; int N; int tile0; };
struct TPack { TDesc d[19]; };

__global__ __launch_bounds__(256) void wtrans_kernel(TPack p)
{
    __shared__ float tl[32][33];
    int tile = blockIdx.x;
    int i = 0;
#pragma unroll 1
    while (i < 18 && tile >= p.d[i + 1].tile0) ++i;
    TDesc d = p.d[i];
    int local = tile - d.tile0;
    int ktiles = d.K >> 5;
    int lk = local % ktiles, ln_ = local / ktiles;
    int k0 = lk * 32, n0 = ln_ * 32;
    int tx = threadIdx.x & 31, ty = threadIdx.x >> 5;
#pragma unroll
    for (int r = 0; r < 4; ++r) {
        int row = ty * 4 + r;
        tl[row][tx] = d.src[(size_t)(k0 + row) * d.N + n0 + tx];
    }
    __syncthreads();
#pragma unroll
    for (int r = 0; r < 4; ++r) {
        int row = ty * 4 + r;
        d.dst[(size_t)(n0 + row) * d.K + k0 + tx] = rne_bf16(tl[tx][row]);
    }
}

// ---------------- LayerNorm over C=128, 4 rows per block (1 wave/row), bf16 out ----------------
__global__ __launch_bounds__(256) void ln128_kernel(const float* __restrict__ in,
    const float* __restrict__ g, const float* __restrict__ b, u16* __restrict__ out)
{
    int w = threadIdx.x >> 6, lane = threadIdx.x & 63;
    int p = blockIdx.x * 4 + w;
    float2 v = reinterpret_cast<const float2*>(in + (size_t)p * CH)[lane];
    float s = v.x + v.y, sq = v.x * v.x + v.y * v.y;
#pragma unroll
    for (int o = 32; o > 0; o >>= 1) { s += __shfl_xor(s, o); sq += __shfl_xor(sq, o); }
    float mean = s * (1.0f / CH);
    float inv = rsqrtf(sq * (1.0f / CH) - mean * mean + 1e-5f);
    float2 gg = reinterpret_cast<const float2*>(g)[lane];
    float2 bb = reinterpret_cast<const float2*>(b)[lane];
    ushort2 o;
    o.x = rne_bf16((v.x - mean) * inv * gg.x + bb.x);
    o.y = rne_bf16((v.y - mean) * inv * gg.y + bb.y);
    reinterpret_cast<ushort2*>(out + (size_t)p * CH)[lane] = o;
}

// ---------------- MFMA GEMM: A bf16 [M][K], Bt bf16 [N][K] -> C [M][N] ----------------
// MODE 0: f32 = acc+bias            MODE 1: bf16 = gelu(acc+bias)
// MODE 2: f32 = acc+bias+res       MODE 3: bf16 = acc+bias
// MODE 4: f32 = acc+bias+res AND bf16 mirror
template<int BM, int BN, int MODE>
__global__ __launch_bounds__(256) void mfma_gemm_kernel(
    const u16* __restrict__ A, const u16* __restrict__ Bt,
    const float* __restrict__ bias, const float* __restrict__ res,
    float* __restrict__ Cf, u16* __restrict__ Cb,
    int M, int N, int K)
{
    constexpr int MF = BM / 32, NF = BN / 32;
    __shared__ u16 Als[BM * 64];
    __shared__ u16 Bls[BN * 64];
    char* alsb = reinterpret_cast<char*>(Als);
    char* blsb = reinterpret_cast<char*>(Bls);
    int t = threadIdx.x;
    int m0 = blockIdx.x * BM, n0 = blockIdx.y * BN;
    int lane = t & 63, w = t >> 6;
    int wr = w >> 1, wc = w & 1;
    f32x4 acc[MF][NF] = {};
    for (int k0 = 0; k0 < K; k0 += 64) {
#pragma unroll
        for (int i = 0; i < BM / 32; ++i) {
            int s = t + i * 256, row = s >> 3, ch = (s & 7) * 8;
            bf16x8 v = *reinterpret_cast<const bf16x8*>(A + (size_t)(m0 + row) * K + k0 + ch);
            *reinterpret_cast<bf16x8*>(alsb + row * 128 + ((ch * 2) ^ ((row & 7) << 4))) = v;
        }
#pragma unroll
        for (int i = 0; i < BN / 32; ++i) {
            int s = t + i * 256, row = s >> 3, ch = (s & 7) * 8;
            bf16x8 v = *reinterpret_cast<const bf16x8*>(Bt + (size_t)(n0 + row) * K + k0 + ch);
            *reinterpret_cast<bf16x8*>(blsb + row * 128 + ((ch * 2) ^ ((row & 7) << 4))) = v;
        }
        __syncthreads();
#pragma unroll
        for (int kk = 0; kk < 2; ++kk) {
            int kb = kk * 64 + (lane >> 4) * 16;
            bf16x8 af[MF], bfr[NF];
#pragma unroll
            for (int mi = 0; mi < MF; ++mi) {
                int row = wr * (BM / 2) + mi * 16 + (lane & 15);
                af[mi] = *reinterpret_cast<const bf16x8*>(alsb + row * 128 + (kb ^ ((row & 7) << 4)));
            }
#pragma unroll
            for (int ni = 0; ni < NF; ++ni) {
                int row = wc * (BN / 2) + ni * 16 + (lane & 15);
                bfr[ni] = *reinterpret_cast<const bf16x8*>(blsb + row * 128 + (kb ^ ((row & 7) << 4)));
            }
#pragma unroll
            for (int mi = 0; mi < MF; ++mi)
#pragma unroll
                for (int ni = 0; ni < NF; ++ni)
                    acc[mi][ni] = __builtin_amdgcn_mfma_f32_16x16x32_bf16(af[mi], bfr[ni], acc[mi][ni], 0, 0, 0);
        }
        __syncthreads();
    }
    int fq = lane >> 4, fr = lane & 15;
#pragma unroll
    for (int mi = 0; mi < MF; ++mi) {
#pragma unroll
        for (int ni = 0; ni < NF; ++ni) {
            int col = n0 + wc * (BN / 2) + ni * 16 + fr;
            float bv = bias[col];
#pragma unroll
            for (int j = 0; j < 4; ++j) {
                int row = m0 + wr * (BM / 2) + mi * 16 + fq * 4 + j;
                float v = acc[mi][ni][j] + bv;
                if constexpr (MODE == 1) {
                    Cb[(size_t)row * N + col] = rne_bf16(gelu_f(v));
                } else if constexpr (MODE == 2) {
                    Cf[(size_t)row * N + col] = v + res[(size_t)row * N + col];
                } else if constexpr (MODE == 3) {
                    Cb[(size_t)row * N + col] = rne_bf16(v);
                } else if constexpr (MODE == 4) {
                    float r2 = v + res[(size_t)row * N + col];
                    Cf[(size_t)row * N + col] = r2;
                    Cb[(size_t)row * N + col] = rne_bf16(r2);
                } else {
                    Cf[(size_t)row * N + col] = v;
                }
            }
        }
    }
}

// ---------------- conv as MFMA implicit GEMM: M=3136 (BM=32), N=512 (BN=64), K=2304 ----------------
__global__ __launch_bounds__(256) void conv_mfma_kernel(
    const u16* __restrict__ Xb, const u16* __restrict__ Xc,
    const u16* __restrict__ Wt, float* __restrict__ Out)
{
    __shared__ u16 Als[32 * 64];
    __shared__ u16 Bls[64 * 64];
    char* alsb = reinterpret_cast<char*>(Als);
    char* blsb = reinterpret_cast<char*>(Bls);
    int t = threadIdx.x;
    int m0 = blockIdx.x * 32, n0 = blockIdx.y * 64;
    int lane = t & 63, w = t >> 6, wr = w >> 1, wc = w & 1;

    int arow = t >> 3, ach = (t & 7) * 8;
    int pm = m0 + arow;
    int b = pm / 784; int rem = pm - b * 784;
    int oi = rem / 28, oj = rem - oi * 28;
    int pb = b * 56, ib = 2 * oi - 1, jb = 2 * oj - 1;

    f32x4 acc[2] = {};
    for (int k0 = 0; k0 < 2304; k0 += 64) {
        {
            int k = k0 + ach;
            int tap = k >> 8, c = k & 255;
            int ky = (tap * 11) >> 5, kx = tap - ky * 3;
            int ii = ib + ky, jj = jb + kx;
            bf16x8 v = {};
            if ((unsigned)ii < 56u && (unsigned)jj < 56u) {
                const u16* src = (c < 128) ? Xb : Xc;
                v = *reinterpret_cast<const bf16x8*>(src + (size_t)((pb + ii) * 56 + jj) * 128 + (c & 127));
            }
            *reinterpret_cast<bf16x8*>(alsb + arow * 128 + ((ach * 2) ^ ((arow & 7) << 4))) = v;
        }
#pragma unroll
        for (int i = 0; i < 2; ++i) {
            int s = t + i * 256, row = s >> 3, ch = (s & 7) * 8;
            bf16x8 v = *reinterpret_cast<const bf16x8*>(Wt + (size_t)(n0 + row) * 2304 + k0 + ch);
            *reinterpret_cast<bf16x8*>(blsb + row * 128 + ((ch * 2) ^ ((row & 7) << 4))) = v;
        }
        __syncthreads();
#pragma unroll
        for (int kk = 0; kk < 2; ++kk) {
            int kb = kk * 64 + (lane >> 4) * 16;
            int row_a = wr * 16 + (lane & 15);
            bf16x8 af = *reinterpret_cast<const bf16x8*>(alsb + row_a * 128 + (kb ^ ((row_a & 7) << 4)));
#pragma unroll
            for (int ni = 0; ni < 2; ++ni) {
                int row = wc * 32 + ni * 16 + (lane & 15);
                bf16x8 bfr = *reinterpret_cast<const bf16x8*>(blsb + row * 128 + (kb ^ ((row & 7) << 4)));
                acc[ni] = __builtin_amdgcn_mfma_f32_16x16x32_bf16(af, bfr, acc[ni], 0, 0, 0);
            }
        }
        __syncthreads();
    }
    int fq = lane >> 4, fr = lane & 15;
#pragma unroll
    for (int ni = 0; ni < 2; ++ni) {
        int col = n0 + wc * 32 + ni * 16 + fr;
#pragma unroll
        for (int j = 0; j < 4; ++j) {
            int row = m0 + wr * 16 + fq * 4 + j;
            Out[(size_t)row * 512 + col] = acc[ni][j];
        }
    }
}

// ---------------- MFMA neighborhood attention ----------------
__global__ __launch_bounds__(256) void na_mfma_kernel(
    const u16* __restrict__ Q, int qld,
    const u16* __restrict__ Kx, const u16* __restrict__ Vx, int kvld,
    const float* __restrict__ rpb, u16* __restrict__ Out)
{
    __shared__ float Sls[32 * 145];        // aliased as Kls (144*40 u16)
    __shared__ u16 Qls[32 * 40];
    __shared__ u16 Pls[32 * 168];
    __shared__ u16 Vtls[32 * 168];
    __shared__ float rls[169];
    u16* Kls = reinterpret_cast<u16*>(Sls);

    int t = threadIdx.x, lane = t & 63, w = t >> 6;
    int h = blockIdx.y, blk = blockIdx.x;
    int b = blk / 98; int rem = blk - b * 98;
    int ti = rem / 7, tj = rem - ti * 7;
    int i0 = ti * 4, j0 = tj * 8;
    int r0 = min(max(i0 - 3, 0), 46), c0 = min(max(j0 - 3, 0), 42);
    int gbase = (b * 56 + r0) * 56 + c0;

    {
        uint4 z = make_uint4(0, 0, 0, 0);
        uint4* pz = reinterpret_cast<uint4*>(Pls);
        uint4* vz = reinterpret_cast<uint4*>(Vtls);
        for (int i = t; i < 672; i += 256) { pz[i] = z; vz[i] = z; }
    }
    __syncthreads();

    for (int idx = t; idx < 560; idx += 256) {
        int r = idx >> 2, c8 = (idx & 3) * 8;
        int ur = r / 14, uc = r - ur * 14;
        size_t g = (size_t)(gbase + ur * 56 + uc) * kvld + h * 32 + c8;
        *reinterpret_cast<bf16x8*>(Kls + r * 40 + c8) = *reinterpret_cast<const bf16x8*>(Kx + g);
        bf16x8 vv = *reinterpret_cast<const bf16x8*>(Vx + g);
#pragma unroll
        for (int e = 0; e < 8; ++e) Vtls[(c8 + e) * 168 + r] = (u16)vv[e];
    }
    if (t < 16) {
        int r = 140 + (t >> 2), c8 = (t & 3) * 8;
        bf16x8 z8 = {};
        *reinterpret_cast<bf16x8*>(Kls + r * 40 + c8) = z8;
    }
    if (t < 128) {
        int q = t >> 2, c8 = (t & 3) * 8;
        int qi = q >> 3, qj = q & 7;
        *reinterpret_cast<bf16x8*>(Qls + q * 40 + c8) =
            *reinterpret_cast<const bf16x8*>(Q + (size_t)((b * 56 + i0 + qi) * 56 + j0 + qj) * qld + h * 32 + c8);
    }
    if (t < 169) rls[t] = rpb[h * 169 + t];
    __syncthreads();

    f32x4 sacc[3][2] = {};
#pragma unroll
    for (int pi = 0; pi < 3; ++pi) {
        int pt = w + pi * 4;
        if (pt < 9) {
            bf16x8 bfrag = *reinterpret_cast<const bf16x8*>(Kls + (pt * 16 + (lane & 15)) * 40 + (lane >> 4) * 8);
#pragma unroll
            for (int qt = 0; qt < 2; ++qt) {
                bf16x8 afrag = *reinterpret_cast<const bf16x8*>(Qls + (qt * 16 + (lane & 15)) * 40 + (lane >> 4) * 8);
                sacc[pi][qt] = __builtin_amdgcn_mfma_f32_16x16x32_bf16(afrag, bfrag, sacc[pi][qt], 0, 0, 0);
            }
        }
    }
    __syncthreads();
#pragma unroll
    for (int pi = 0; pi < 3; ++pi) {
        int pt = w + pi * 4;
        if (pt < 9) {
#pragma unroll
            for (int qt = 0; qt < 2; ++qt) {
                int p = pt * 16 + (lane & 15), qr = qt * 16 + (lane >> 4) * 4;
#pragma unroll
                for (int j = 0; j < 4; ++j) Sls[(qr + j) * 145 + p] = sacc[pi][qt][j];
            }
        }
    }
    __syncthreads();

    int ai = lane / 7, aj = lane - ai * 7;
    for (int qq = 0; qq < 8; ++qq) {
        int q = w * 8 + qq;
        int qi = q >> 3, qj = q & 7;
        int i = i0 + qi, j = j0 + qj;
        int si = min(max(i - 3, 0), 49), sj = min(max(j - 3, 0), 49);
        int pu_base = (si - r0) * 14 + (sj - c0);
        float s = -1e30f; int pu = 0;
        if (lane < 49) {
            pu = pu_base + ai * 14 + aj;
            s = Sls[q * 145 + pu] * 0.17677669529663687f
              + rls[(si - i + 6 + ai) * 13 + (sj - j + 6 + aj)];
        }
        float m = s;
#pragma unroll
        for (int o = 32; o > 0; o >>= 1) m = fmaxf(m, __shfl_xor(m, o));
        float e = (lane < 49) ? expf(s - m) : 0.f;
        float sum = e;
#pragma unroll
        for (int o = 32; o > 0; o >>= 1) sum += __shfl_xor(sum, o);
        if (lane < 49) Pls[q * 168 + pu] = rne_bf16(e / sum);
    }
    __syncthreads();

    int qt = w >> 1, ct = w & 1;
    f32x4 oacc = {};
#pragma unroll
    for (int k = 0; k < 5; ++k) {
        bf16x8 pa = *reinterpret_cast<const bf16x8*>(Pls + (qt * 16 + (lane & 15)) * 168 + k * 32 + (lane >> 4) * 8);
        bf16x8 vb = *reinterpret_cast<const bf16x8*>(Vtls + (ct * 16 + (lane & 15)) * 168 + k * 32 + (lane >> 4) * 8);
        oacc = __builtin_amdgcn_mfma_f32_16x16x32_bf16(pa, vb, oacc, 0, 0, 0);
    }
    int ch = ct * 16 + (lane & 15);
#pragma unroll
    for (int j = 0; j < 4; ++j) {
        int q = qt * 16 + (lane >> 4) * 4 + j;
        int qi = q >> 3, qj = q & 7;
        Out[(size_t)((b * 56 + i0 + qi) * 56 + j0 + qj) * CH + h * 32 + ch] = rne_bf16(oacc[j]);
    }
}

// ---------------- final LayerNorm over 512, 4 rows/block, write f32 ----------------
__global__ __launch_bounds__(256) void ln512_out_kernel(const float* __restrict__ in,
    const float* __restrict__ g, const float* __restrict__ b, float* __restrict__ out)
{
    int w = threadIdx.x >> 6, lane = threadIdx.x & 63;
    int p = blockIdx.x * 4 + w;
    const float4* ip = reinterpret_cast<const float4*>(in + (size_t)p * 512);
    float4 v0 = ip[lane * 2], v1 = ip[lane * 2 + 1];
    float vals[8] = { v0.x, v0.y, v0.z, v0.w, v1.x, v1.y, v1.z, v1.w };
    float s = 0.f, sq = 0.f;
#pragma unroll
    for (int q = 0; q < 8; ++q) { s += vals[q]; sq += vals[q] * vals[q]; }
#pragma unroll
    for (int o = 32; o > 0; o >>= 1) { s += __shfl_xor(s, o); sq += __shfl_xor(sq, o); }
    float mean = s * (1.0f / 512.0f);
    float inv = rsqrtf(sq * (1.0f / 512.0f) - mean * mean + 1e-5f);
#pragma unroll
    for (int q = 0; q < 8; ++q) {
        int c = lane * 8 + q;
        out[(size_t)p * 512 + c] = (vals[q] - mean) * inv * g[c] + b[c];
    }
}

extern "C" void kernel_launch(void* const* d_in, const int* in_sizes, int n_in,
                              void* d_out, int out_size, void* d_ws, size_t ws_size,
                              hipStream_t stream)
{
    const float* X      = (const float*)d_in[0];
    const float* XM     = (const float*)d_in[1];
    const float* sa_n1g = (const float*)d_in[2];
    const float* sa_n1b = (const float*)d_in[3];
    const float* sa_qkvw= (const float*)d_in[4];
    const float* sa_qkvb= (const float*)d_in[5];
    const float* sa_rpb = (const float*)d_in[6];
    const float* sa_pw  = (const float*)d_in[7];
    const float* sa_pb  = (const float*)d_in[8];
    const float* sa_n2g = (const float*)d_in[9];
    const float* sa_n2b = (const float*)d_in[10];
    const float* sa_f1w = (const float*)d_in[11];
    const float* sa_f1b = (const float*)d_in[12];
    const float* sa_f2w = (const float*)d_in[13];
    const float* sa_f2b = (const float*)d_in[14];
    const float* cr_n1g = (const float*)d_in[15];
    const float* cr_n1b = (const float*)d_in[16];
    const float* cr_qw  = (const float*)d_in[17];
    const float* cr_qb  = (const float*)d_in[18];
    const float* cr_kvw = (const float*)d_in[19];
    const float* cr_kvb = (const float*)d_in[20];
    const float* cr_rpb = (const float*)d_in[21];
    const float* cr_pw  = (const float*)d_in[22];
    const float* cr_pb  = (const float*)d_in[23];
    const float* cr_n2g = (const float*)d_in[24];
    const float* cr_n2b = (const float*)d_in[25];
    const float* cr_f1w = (const float*)d_in[26];
    const float* cr_f1b = (const float*)d_in[27];
    const float* cr_f2w = (const float*)d_in[28];
    const float* cr_f2b = (const float*)d_in[29];
    const float* dconvw = (const float*)d_in[30];
    const float* ds_ng  = (const float*)d_in[31];
    const float* ds_nb  = (const float*)d_in[32];

    const size_t NC = (size_t)NPIX * CH;       // 1,605,632
    float* ws   = (float*)d_ws;
    float* xb   = ws;                          // [NPIX,128] f32 x state
    float* xcb  = xb + NC;                     // [NPIX,128] f32 x_cross state
    float* bigR = xcb + NC;                    // region, 2*NC f32: fc1 bf16 out OR conv f32 out
    u16* bigb   = (u16*)bigR;                  // [NPIX,512] bf16 (fc1)
    u16* hnb    = (u16*)(bigR + 2 * NC);       // [NPIX,128] bf16 LN out
    u16* attnb  = hnb + NC;                    // [NPIX,128] bf16 NA out
    u16* xcbbf  = attnb + NC;                  // [NPIX,128] bf16 mirror of xcb state
    u16* xbbf   = xcbbf + NC;                  // [NPIX,128] bf16 mirror of xb (for conv)
    u16* qkvb   = xbbf + NC;                   // [NPIX,384] bf16 qkv / kv
    u16* bufQb  = qkvb + (size_t)NPIX * 384;   // [NPIX,128] bf16 cross q
    u16* wa     = bufQb + NC;                  // bf16 weight arena (~2.0M elems)

    // ---- weight arena layout + transpose descriptors ----
    TPack tp;
    int tile = 0, idx = 0;
    u16* p = wa;
    u16* qkvt[2]; u16* pwt[2]; u16* f1t[2]; u16* f2t[2];
    u16* qt[2];   u16* kvt[2]; u16* cpt[2]; u16* cf1t[2];
    u16* cf2t[2]; u16* convt;
    auto add = [&](const float* s, u16*& dst, int K, int N) {
        dst = p;
        tp.d[idx].src = s; tp.d[idx].dst = p; tp.d[idx].K = K; tp.d[idx].N = N; tp.d[idx].tile0 = tile;
        tile += (K / 32) * (N / 32); p += (size_t)K * N; ++idx;
    };
    for (int l = 0; l < 2; ++l) add(sa_qkvw + (size_t)l * 128 * 384, qkvt[l], 128, 384);
    for (int l = 0; l < 2; ++l) add(sa_pw   + (size_t)l * 128 * 128, pwt[l],  128, 128);
    for (int l = 0; l < 2; ++l) add(sa_f1w  + (size_t)l * 128 * 512, f1t[l],  128, 512);
    for (int l = 0; l < 2; ++l) add(sa_f2w  + (size_t)l * 512 * 128, f2t[l],  512, 128);
    for (int l = 0; l < 2; ++l) add(cr_qw   + (size_t)l * 128 * 128, qt[l],   128, 128);
    for (int l = 0; l < 2; ++l) add(cr_kvw  + (size_t)l * 128 * 256, kvt[l],  128, 256);
    for (int l = 0; l < 2; ++l) add(cr_pw   + (size_t)l * 128 * 128, cpt[l],  128, 128);
    for (int l = 0; l < 2; ++l) add(cr_f1w  + (size_t)l * 128 * 512, cf1t[l], 128, 512);
    for (int l = 0; l < 2; ++l) add(cr_f2w  + (size_t)l * 512 * 128, cf2t[l], 512, 128);
    add(dconvw, convt, 2304, 512);

    wtrans_kernel<<<tile, 256, 0, stream>>>(tp);

    const int n4 = NPIX * CH / 4;
    dup_kernel<<<(n4 + 255) / 256, 256, 0, stream>>>(X, xb, xcb, xcbbf, n4);

    const int GM = NPIX / 64;   // 196

    // ---- self-attention layers ----
    for (int l = 0; l < 2; ++l) {
        ln128_kernel<<<NPIX / 4, 256, 0, stream>>>(xb, sa_n1g + l * CH, sa_n1b + l * CH, hnb);
        mfma_gemm_kernel<64, 64, 3><<<dim3(GM, 6), 256, 0, stream>>>(
            hnb, qkvt[l], sa_qkvb + l * 384, nullptr, nullptr, qkvb, NPIX, 384, 128);
        na_mfma_kernel<<<dim3(392, 4), 256, 0, stream>>>(qkvb, 384, qkvb + 128, qkvb + 256, 384,
                                                         sa_rpb + l * HEADS * 169, attnb);
        mfma_gemm_kernel<64, 64, 2><<<dim3(GM, 2), 256, 0, stream>>>(
            attnb, pwt[l], sa_pb + l * CH, xb, xb, nullptr, NPIX, 128, 128);
        ln128_kernel<<<NPIX / 4, 256, 0, stream>>>(xb, sa_n2g + l * CH, sa_n2b + l * CH, hnb);
        mfma_gemm_kernel<64, 64, 1><<<dim3(GM, 8), 256, 0, stream>>>(
            hnb, f1t[l], sa_f1b + l * HID, nullptr, nullptr, bigb, NPIX, 512, 128);
        mfma_gemm_kernel<64, 64, 4><<<dim3(GM, 2), 256, 0, stream>>>(
            bigb, f2t[l], sa_f2b + l * CH, xb, xb, xbbf, NPIX, 128, 512);
    }

    // ---- cross layers ----
    for (int l = 0; l < 2; ++l) {
        ln128_kernel<<<NPIX / 4, 256, 0, stream>>>(XM, cr_n1g + l * CH, cr_n1b + l * CH, hnb);
        mfma_gemm_kernel<64, 64, 3><<<dim3(GM, 2), 256, 0, stream>>>(
            xcbbf, qt[l], cr_qb + l * CH, nullptr, nullptr, bufQb, NPIX, 128, 128);
        mfma_gemm_kernel<64, 64, 3><<<dim3(GM, 4), 256, 0, stream>>>(
            hnb, kvt[l], cr_kvb + l * 256, nullptr, nullptr, qkvb, NPIX, 256, 128);
        na_mfma_kernel<<<dim3(392, 4), 256, 0, stream>>>(bufQb, 128, qkvb, qkvb + 128, 256,
                                                         cr_rpb + l * HEADS * 169, attnb);
        mfma_gemm_kernel<64, 64, 2><<<dim3(GM, 2), 256, 0, stream>>>(
            attnb, cpt[l], cr_pb + l * CH, XM, xcb, nullptr, NPIX, 128, 128);
        ln128_kernel<<<NPIX / 4, 256, 0, stream>>>(xcb, cr_n2g + l * CH, cr_n2b + l * CH, hnb);
        mfma_gemm_kernel<64, 64, 1><<<dim3(GM, 8), 256, 0, stream>>>(
            hnb, cf1t[l], cr_f1b + l * HID, nullptr, nullptr, bigb, NPIX, 512, 128);
        mfma_gemm_kernel<64, 64, 4><<<dim3(GM, 2), 256, 0, stream>>>(
            bigb, cf2t[l], cr_f2b + l * CH, xcb, xcb, xcbbf, NPIX, 128, 512);
    }

    // ---- downsample conv (MFMA implicit GEMM) + final LN ----
    conv_mfma_kernel<<<dim3(3136 / 32, 512 / 64), 256, 0, stream>>>(xbbf, xcbbf, convt, bigR);
    ln512_out_kernel<<<3136 / 4, 256, 0, stream>>>(bigR, ds_ng, ds_nb, (float*)d_out);
}